// Round 4
// baseline (2467.466 us; speedup 1.0000x reference)
//
#include <hip/hip_runtime.h>

// ---------------------------------------------------------------------------
// E89 ResidualStateCell.
// Precision architecture (recurrence-critical channels get ~fp32):
//   k, v, decay  -> split-bf16 (hi+lo) MFMA GEMM, fp32 storage   [feed S]
//   q, Sq, Wout  -> fp16 (read-out only, local error ~1e-4 rel)  [don't feed S]
//   scan         -> fp32 registers, libm tanhf/expf
// Memory plan (ws proven-safe budget ~170 MB):
//   ws:  x hi/lo (33.6, later aliased by Sq fp16) | W-split buf (14.7, reused
//        serially by Wk/Wv/Wq/Wa) | k fp32 (58.7) | v fp32 (58.7) | Wout fp16 (3.7)
//   d_out head (out region, dead until final GEMM): q fp16 (29.4) + decay (1.8)
// ---------------------------------------------------------------------------

typedef __attribute__((ext_vector_type(8))) __bf16 bf16x8;
typedef __attribute__((ext_vector_type(8))) _Float16 f16x8;
typedef __attribute__((ext_vector_type(4))) float f32x4;

#define T_LEN 2048
#define BB 4
#define HH 56
#define NS 32
#define DIM 1024
#define KD 1792            // H*NS
#define MROWS 8192         // T_LEN*BB

__device__ __forceinline__ float bf2f(unsigned short u) {
    return __uint_as_float(((unsigned int)u) << 16);
}
__device__ __forceinline__ unsigned short f2bf(float f) {
    unsigned int u = __float_as_uint(f);
    u += 0x7fffu + ((u >> 16) & 1u);          // round-to-nearest-even
    return (unsigned short)(u >> 16);
}
__device__ __forceinline__ unsigned short f2h(float f) {
    union { _Float16 h; unsigned short u; } cv;
    cv.h = (_Float16)f;                       // RNE
    return cv.u;
}
__device__ __forceinline__ float h2f(unsigned short u) {
    union { unsigned short u; _Float16 h; } cv;
    cv.u = u;
    return (float)cv.h;
}

__device__ __forceinline__ void gload_lds16(const void* g, void* l) {
    __builtin_amdgcn_global_load_lds(
        (const __attribute__((address_space(1))) unsigned int*)g,
        (__attribute__((address_space(3))) unsigned int*)l, 16, 0, 0);
}

// ---------------------------------------------------------------------------
// f32 -> (bf16 hi, bf16 lo) split cast, 8 elements / thread
// ---------------------------------------------------------------------------
__global__ void cast_split_kernel(const float* __restrict__ in,
                                  unsigned short* __restrict__ hi,
                                  unsigned short* __restrict__ lo, int n8) {
    int i = blockIdx.x * blockDim.x + threadIdx.x;
    if (i >= n8) return;
    const float4* p = (const float4*)in + (size_t)i * 2;
    float4 a = p[0], b = p[1];
    float xs[8] = {a.x, a.y, a.z, a.w, b.x, b.y, b.z, b.w};
    unsigned int ho[4], lv[4];
#pragma unroll
    for (int c = 0; c < 4; ++c) {
        unsigned short h0 = f2bf(xs[2 * c]);
        unsigned short h1 = f2bf(xs[2 * c + 1]);
        unsigned short l0 = f2bf(xs[2 * c] - bf2f(h0));
        unsigned short l1 = f2bf(xs[2 * c + 1] - bf2f(h1));
        ho[c] = (unsigned int)h0 | ((unsigned int)h1 << 16);
        lv[c] = (unsigned int)l0 | ((unsigned int)l1 << 16);
    }
    ((uint4*)hi)[i] = (uint4){ho[0], ho[1], ho[2], ho[3]};
    ((uint4*)lo)[i] = (uint4){lv[0], lv[1], lv[2], lv[3]};
}

// ---------------------------------------------------------------------------
// f32 -> fp16 cast, 8 elements / thread (for Wout)
// ---------------------------------------------------------------------------
__global__ void cast_half_kernel(const float* __restrict__ in,
                                 unsigned short* __restrict__ out, int n8) {
    int i = blockIdx.x * blockDim.x + threadIdx.x;
    if (i >= n8) return;
    const float4* p = (const float4*)in + (size_t)i * 2;
    float4 a = p[0], b = p[1];
    uint4 o;
    o.x = (unsigned int)f2h(a.x) | ((unsigned int)f2h(a.y) << 16);
    o.y = (unsigned int)f2h(a.z) | ((unsigned int)f2h(a.w) << 16);
    o.z = (unsigned int)f2h(b.x) | ((unsigned int)f2h(b.y) << 16);
    o.w = (unsigned int)f2h(b.z) | ((unsigned int)f2h(b.w) << 16);
    ((uint4*)out)[i] = o;
}

// ---------------------------------------------------------------------------
// Split MFMA GEMM core: Y[m,n] = sum_k A[m,k]*B[n,k], A=Ah+Al, B=Bh+Bl.
// 128x128 tile, BK=32, 256 threads = 4 waves (2x2), 16x16x32 bf16 MFMA x3.
// ---------------------------------------------------------------------------
__device__ __forceinline__ void gemm_split(
    const unsigned short* __restrict__ Ah, const unsigned short* __restrict__ Al,
    const unsigned short* __restrict__ Bh, const unsigned short* __restrict__ Bl,
    int m0, int n0, int K, int bmax,
    unsigned short* AsH, unsigned short* AsL,
    unsigned short* BsH, unsigned short* BsL,
    f32x4 (&acc)[4][4]) {
    const int tid  = threadIdx.x;
    const int lane = tid & 63;
    const int wave = tid >> 6;
    const int wm = wave >> 1, wn = wave & 1;
    const int lr = lane & 15, lkb = lane >> 4;

#pragma unroll
    for (int fr = 0; fr < 4; ++fr)
#pragma unroll
        for (int fc = 0; fc < 4; ++fc) acc[fr][fc] = (f32x4){0.f, 0.f, 0.f, 0.f};

    auto stage = [&](int kt) {
#pragma unroll
        for (int c = 0; c < 2; ++c) {
            int i = c * 256 + tid;
            int r = i >> 2, kk = (i & 3) << 3;
            size_t ao = (size_t)(m0 + r) * K + kt + kk;
            int br = n0 + r; if (br > bmax) br = bmax;
            size_t bo = (size_t)br * K + kt + kk;
            gload_lds16(Ah + ao, AsH + i * 8);
            gload_lds16(Al + ao, AsL + i * 8);
            gload_lds16(Bh + bo, BsH + i * 8);
            gload_lds16(Bl + bo, BsL + i * 8);
        }
    };

    stage(0);
    const int nk = K >> 5;
    for (int t = 0; t < nk; ++t) {
        __syncthreads();                       // drains vmcnt -> LDS tiles ready
        bf16x8 ah[4], al[4], bh[4], bl[4];
#pragma unroll
        for (int f = 0; f < 4; ++f) {
            int ai = (wm * 64 + f * 16 + lr) * 32 + lkb * 8;
            int bi = (wn * 64 + f * 16 + lr) * 32 + lkb * 8;
            ah[f] = *(const bf16x8*)(AsH + ai);
            al[f] = *(const bf16x8*)(AsL + ai);
            bh[f] = *(const bf16x8*)(BsH + bi);
            bl[f] = *(const bf16x8*)(BsL + bi);
        }
#pragma unroll
        for (int fr = 0; fr < 4; ++fr)
#pragma unroll
            for (int fc = 0; fc < 4; ++fc) {
                acc[fr][fc] = __builtin_amdgcn_mfma_f32_16x16x32_bf16(
                    ah[fr], bh[fc], acc[fr][fc], 0, 0, 0);
                acc[fr][fc] = __builtin_amdgcn_mfma_f32_16x16x32_bf16(
                    ah[fr], bl[fc], acc[fr][fc], 0, 0, 0);
                acc[fr][fc] = __builtin_amdgcn_mfma_f32_16x16x32_bf16(
                    al[fr], bh[fc], acc[fr][fc], 0, 0, 0);
            }
        __syncthreads();                       // all waves done reading LDS
        if (t + 1 < nk) stage((t + 1) << 5);
    }
}

// ---------------------------------------------------------------------------
// Projection GEMM over x (M=8192, K=1024).
// mode 0: silu -> fp32 dstF   (k, v — recurrence-critical)
// mode 1: silu -> fp16 dstH   (q — read-out only)
// mode 2: decay computation -> fp32 decayb (n < 56)
// ---------------------------------------------------------------------------
__global__ __launch_bounds__(256) void proj_gemm_kernel(
    const unsigned short* __restrict__ xh, const unsigned short* __restrict__ xl,
    const unsigned short* __restrict__ Bh, const unsigned short* __restrict__ Bl,
    const float* __restrict__ A_log, const float* __restrict__ dt_bias,
    float* __restrict__ dstF, unsigned short* __restrict__ dstH,
    float* __restrict__ decayb, int mode) {
    __shared__ __align__(16) unsigned short AsH[128 * 32];
    __shared__ __align__(16) unsigned short AsL[128 * 32];
    __shared__ __align__(16) unsigned short BsH[128 * 32];
    __shared__ __align__(16) unsigned short BsL[128 * 32];

    int m0 = blockIdx.y * 128;
    int n0 = blockIdx.x * 128;
    int bmax = (mode == 2) ? (HH - 1) : (KD - 1);

    f32x4 acc[4][4];
    gemm_split(xh, xl, Bh, Bl, m0, n0, DIM, bmax, AsH, AsL, BsH, BsL, acc);

    const int lane = threadIdx.x & 63, wave = threadIdx.x >> 6;
    const int wm = wave >> 1, wn = wave & 1, lr = lane & 15, lkb = lane >> 4;

#pragma unroll
    for (int fr = 0; fr < 4; ++fr)
#pragma unroll
        for (int fc = 0; fc < 4; ++fc)
#pragma unroll
            for (int v = 0; v < 4; ++v) {
                int m = m0 + wm * 64 + fr * 16 + lkb * 4 + v;
                int n = n0 + wn * 64 + fc * 16 + lr;
                float y = acc[fr][fc][v];
                if (mode == 0) {
                    float s = y / (1.f + expf(-y));            // silu, libm exp
                    dstF[(size_t)m * KD + n] = s;
                } else if (mode == 1) {
                    float s = y / (1.f + expf(-y));
                    dstH[(size_t)m * KD + n] = f2h(s);
                } else if (n < HH) {
                    float z = y + dt_bias[n];
                    float sp = (z > 20.f) ? z : log1pf(expf(z));    // softplus
                    decayb[(size_t)m * HH + n] = expf(-expf(A_log[n]) * sp);
                }
            }
}

// ---------------------------------------------------------------------------
// Output GEMM (fp16): out = Sq @ Wout^T, f32 store.
// ---------------------------------------------------------------------------
__global__ __launch_bounds__(256) void out_gemm_kernel(
    const unsigned short* __restrict__ Sq, const unsigned short* __restrict__ Wo,
    float* __restrict__ out) {
    __shared__ __align__(16) unsigned short As[128 * 32];
    __shared__ __align__(16) unsigned short Bs[128 * 32];
    int m0 = blockIdx.y * 128, n0 = blockIdx.x * 128;

    const int tid  = threadIdx.x;
    const int lane = tid & 63;
    const int wave = tid >> 6;
    const int wm = wave >> 1, wn = wave & 1;
    const int lr = lane & 15, lkb = lane >> 4;

    f32x4 acc[4][4];
#pragma unroll
    for (int fr = 0; fr < 4; ++fr)
#pragma unroll
        for (int fc = 0; fc < 4; ++fc) acc[fr][fc] = (f32x4){0.f, 0.f, 0.f, 0.f};

    auto stage = [&](int kt) {
#pragma unroll
        for (int c = 0; c < 2; ++c) {
            int i = c * 256 + tid;
            int r = i >> 2, kk = (i & 3) << 3;
            gload_lds16(Sq + (size_t)(m0 + r) * KD + kt + kk, As + i * 8);
            gload_lds16(Wo + (size_t)(n0 + r) * KD + kt + kk, Bs + i * 8);
        }
    };

    stage(0);
    const int nk = KD >> 5;
    for (int t = 0; t < nk; ++t) {
        __syncthreads();
        f16x8 af[4], bf[4];
#pragma unroll
        for (int f = 0; f < 4; ++f) {
            af[f] = *(const f16x8*)(As + (wm * 64 + f * 16 + lr) * 32 + lkb * 8);
            bf[f] = *(const f16x8*)(Bs + (wn * 64 + f * 16 + lr) * 32 + lkb * 8);
        }
#pragma unroll
        for (int fr = 0; fr < 4; ++fr)
#pragma unroll
            for (int fc = 0; fc < 4; ++fc)
                acc[fr][fc] = __builtin_amdgcn_mfma_f32_16x16x32_f16(
                    af[fr], bf[fc], acc[fr][fc], 0, 0, 0);
        __syncthreads();
        if (t + 1 < nk) stage((t + 1) << 5);
    }

#pragma unroll
    for (int fr = 0; fr < 4; ++fr)
#pragma unroll
        for (int fc = 0; fc < 4; ++fc)
#pragma unroll
            for (int v = 0; v < 4; ++v) {
                int m = m0 + wm * 64 + fr * 16 + lkb * 4 + v;
                int n = n0 + wn * 64 + fc * 16 + lr;
                out[(size_t)m * DIM + n] = acc[fr][fc][v];
            }
}

// ---------------------------------------------------------------------------
// L2 normalization over NS=32: fp32 buffer (k).
// ---------------------------------------------------------------------------
__global__ void l2norm_f32_kernel(float* __restrict__ buf) {
    int g = blockIdx.x * blockDim.x + threadIdx.x;
    const int NG = MROWS * HH;
    if (g >= NG) return;
    int row = g / HH, hh = g - row * HH;
    float* p = buf + (size_t)row * KD + hh * NS;

    float4 u[8];
#pragma unroll
    for (int c = 0; c < 8; ++c) u[c] = ((const float4*)p)[c];
    float ss = 0.f;
#pragma unroll
    for (int c = 0; c < 8; ++c) {
        ss = fmaf(u[c].x, u[c].x, ss); ss = fmaf(u[c].y, u[c].y, ss);
        ss = fmaf(u[c].z, u[c].z, ss); ss = fmaf(u[c].w, u[c].w, ss);
    }
    float sc = 1.f / fmaxf(sqrtf(ss), 1e-12f);
#pragma unroll
    for (int c = 0; c < 8; ++c) {
        u[c].x *= sc; u[c].y *= sc; u[c].z *= sc; u[c].w *= sc;
        ((float4*)p)[c] = u[c];
    }
}

// ---------------------------------------------------------------------------
// L2 normalization over NS=32: fp16 buffer (q), fp32 math.
// ---------------------------------------------------------------------------
__global__ void l2norm_f16_kernel(unsigned short* __restrict__ buf) {
    int g = blockIdx.x * blockDim.x + threadIdx.x;
    const int NG = MROWS * HH;
    if (g >= NG) return;
    int row = g / HH, hh = g - row * HH;
    unsigned short* p = buf + (size_t)row * KD + hh * NS;

    uint4 u[4];
#pragma unroll
    for (int c = 0; c < 4; ++c) u[c] = ((const uint4*)p)[c];
    float ss = 0.f;
    auto acc2 = [&](unsigned int w) {
        float a = h2f((unsigned short)(w & 0xffff));
        float b = h2f((unsigned short)(w >> 16));
        ss = fmaf(a, a, ss); ss = fmaf(b, b, ss);
    };
#pragma unroll
    for (int c = 0; c < 4; ++c) { acc2(u[c].x); acc2(u[c].y); acc2(u[c].z); acc2(u[c].w); }
    float sc = 1.f / fmaxf(sqrtf(ss), 1e-12f);
    auto scl = [&](unsigned int w) -> unsigned int {
        unsigned int lo = f2h(h2f((unsigned short)(w & 0xffff)) * sc);
        unsigned int hi = f2h(h2f((unsigned short)(w >> 16)) * sc);
        return lo | (hi << 16);
    };
#pragma unroll
    for (int c = 0; c < 4; ++c) {
        u[c].x = scl(u[c].x); u[c].y = scl(u[c].y);
        u[c].z = scl(u[c].z); u[c].w = scl(u[c].w);
        ((uint4*)p)[c] = u[c];
    }
}

// ---------------------------------------------------------------------------
// Sequential scan (fp32 math; k,v,decay fp32; q fp16). One block per (b,h);
// 8 lanes per state column j, 4 state elements per lane. Prefetch 8 ahead.
// ---------------------------------------------------------------------------
__global__ __launch_bounds__(256) void scan_kernel(
    const float* __restrict__ kf, const unsigned short* __restrict__ qh,
    const float* __restrict__ vf, const float* __restrict__ decayb,
    const float* __restrict__ S0, unsigned short* __restrict__ Sq,
    float* __restrict__ Sout) {
    const int bh = blockIdx.x;                 // 0..223
    const int b = bh / HH, h = bh - b * HH;
    const int tid = threadIdx.x;
    const int j = tid >> 3, sub = tid & 7, i0 = sub << 2;

    const float* Sp = S0 + (size_t)bh * NS * NS;
    float s0 = Sp[(i0 + 0) * NS + j];
    float s1 = Sp[(i0 + 1) * NS + j];
    float s2 = Sp[(i0 + 2) * NS + j];
    float s3 = Sp[(i0 + 3) * NS + j];

    const size_t cb = (size_t)h * NS;
    constexpr int PF = 8;
    float4 kp[PF]; uint2 qp[PF]; float vp[PF], dp[PF];

#define LOADS(t, K_, Q_, V_, D_)                                   \
    {                                                              \
        size_t ro = ((size_t)(t) * BB + b) * KD + cb;              \
        K_ = *(const float4*)(kf + ro + i0);                       \
        Q_ = *(const uint2*)(qh + ro + i0);                        \
        V_ = vf[ro + j];                                           \
        D_ = decayb[((size_t)(t) * BB + b) * HH + h];              \
    }

#pragma unroll
    for (int p = 0; p < PF; ++p) { LOADS(p, kp[p], qp[p], vp[p], dp[p]); }

    for (int tb = 0; tb < T_LEN; tb += PF) {
#pragma unroll
        for (int p = 0; p < PF; ++p) {
            const int t = tb + p;
            float k0 = kp[p].x, k1 = kp[p].y, k2 = kp[p].z, k3 = kp[p].w;
            float q0 = h2f((unsigned short)(qp[p].x & 0xffff));
            float q1 = h2f((unsigned short)(qp[p].x >> 16));
            float q2 = h2f((unsigned short)(qp[p].y & 0xffff));
            float q3 = h2f((unsigned short)(qp[p].y >> 16));
            float vj = vp[p];
            float d  = dp[p];
            if (t + PF < T_LEN) { LOADS(t + PF, kp[p], qp[p], vp[p], dp[p]); }

            // retrieved_j = sum_i S[i][j]*k_i   (partial + 3-stage butterfly)
            float r = k0 * s0; r = fmaf(k1, s1, r); r = fmaf(k2, s2, r); r = fmaf(k3, s3, r);
            r += __shfl_xor(r, 1, 8);
            r += __shfl_xor(r, 2, 8);
            r += __shfl_xor(r, 4, 8);
            float delta = vj - r;

            float a0 = fmaf(d, s0, k0 * delta);
            float a1 = fmaf(d, s1, k1 * delta);
            float a2 = fmaf(d, s2, k2 * delta);
            float a3 = fmaf(d, s3, k3 * delta);
            s0 += tanhf(a0); s1 += tanhf(a1);
            s2 += tanhf(a2); s3 += tanhf(a3);

            // Sq_j = sum_i S[i][j]*q_i
            float o = q0 * s0; o = fmaf(q1, s1, o); o = fmaf(q2, s2, o); o = fmaf(q3, s3, o);
            o += __shfl_xor(o, 1, 8);
            o += __shfl_xor(o, 2, 8);
            o += __shfl_xor(o, 4, 8);
            if (sub == 0) {
                size_t ro = ((size_t)t * BB + b) * KD + cb;
                Sq[ro + j] = f2h(o);
            }
        }
    }
#undef LOADS

    float* so = Sout + (size_t)bh * NS * NS;
    so[(i0 + 0) * NS + j] = s0;
    so[(i0 + 1) * NS + j] = s1;
    so[(i0 + 2) * NS + j] = s2;
    so[(i0 + 3) * NS + j] = s3;
}

// ---------------------------------------------------------------------------
extern "C" void kernel_launch(void* const* d_in, const int* in_sizes, int n_in,
                              void* d_out, int out_size, void* d_ws, size_t ws_size,
                              hipStream_t stream) {
    const float* x       = (const float*)d_in[0];
    const float* S0      = (const float*)d_in[1];
    const float* Wq      = (const float*)d_in[2];
    const float* Wk      = (const float*)d_in[3];
    const float* Wv      = (const float*)d_in[4];
    const float* Wa      = (const float*)d_in[5];
    const float* A_log   = (const float*)d_in[6];
    const float* dt_bias = (const float*)d_in[7];
    const float* Wout    = (const float*)d_in[8];

    float* out  = (float*)d_out;
    float* Sout = out + (size_t)T_LEN * BB * DIM;

    // --- workspace layout (~169.4 MB peak) ---
    char* w = (char*)d_ws;
    auto alloc = [&](size_t bytes) {
        char* p = w; w += (bytes + 255) & ~(size_t)255; return p;
    };
    unsigned short* xh  = (unsigned short*)alloc((size_t)MROWS * DIM * 2);  // 16.8 MB
    unsigned short* xl  = (unsigned short*)alloc((size_t)MROWS * DIM * 2);  // 16.8 MB
    unsigned short* Wbh = (unsigned short*)alloc((size_t)KD * DIM * 2);     // 3.67 MB (reused)
    unsigned short* Wbl = (unsigned short*)alloc((size_t)KD * DIM * 2);     // 3.67 MB (reused)
    float* kf           = (float*)alloc((size_t)MROWS * KD * 4);            // 58.7 MB
    float* vf           = (float*)alloc((size_t)MROWS * KD * 4);            // 58.7 MB
    unsigned short* Woh = (unsigned short*)alloc((size_t)DIM * KD * 2);     // 3.67 MB
    // Sq (fp16, 29.4 MB) aliases xh+xl (33.6 MB): x dead after last proj GEMM.
    unsigned short* Sq  = xh;

    // --- d_out head as scratch for q (fp16) + decay: dead before out GEMM ---
    unsigned short* qh  = (unsigned short*)d_out;                 // 29.36 MB
    float* decayb       = (float*)((char*)d_out + (size_t)MROWS * KD * 2); // 1.83 MB
    // (29.36 + 1.83 = 31.2 MB <= 33.55 MB out region; Sout at tail is disjoint)

    auto casts = [&](const float* src, unsigned short* hi, unsigned short* lo, size_t n) {
        int n8 = (int)(n / 8);
        cast_split_kernel<<<(n8 + 255) / 256, 256, 0, stream>>>(src, hi, lo, n8);
    };

    casts(x, xh, xl, (size_t)MROWS * DIM);

    // k projection -> fp32
    casts(Wk, Wbh, Wbl, (size_t)KD * DIM);
    proj_gemm_kernel<<<dim3(14, 64), 256, 0, stream>>>(
        xh, xl, Wbh, Wbl, A_log, dt_bias, kf, nullptr, nullptr, 0);
    // v projection -> fp32
    casts(Wv, Wbh, Wbl, (size_t)KD * DIM);
    proj_gemm_kernel<<<dim3(14, 64), 256, 0, stream>>>(
        xh, xl, Wbh, Wbl, A_log, dt_bias, vf, nullptr, nullptr, 0);
    // q projection -> fp16 (d_out scratch)
    casts(Wq, Wbh, Wbl, (size_t)KD * DIM);
    proj_gemm_kernel<<<dim3(14, 64), 256, 0, stream>>>(
        xh, xl, Wbh, Wbl, A_log, dt_bias, nullptr, qh, nullptr, 1);
    // decay -> fp32 (d_out scratch)
    casts(Wa, Wbh, Wbl, (size_t)HH * DIM);
    proj_gemm_kernel<<<dim3(1, 64), 256, 0, stream>>>(
        xh, xl, Wbh, Wbl, A_log, dt_bias, nullptr, nullptr, decayb, 2);

    // Wout -> fp16
    {
        int n8 = (int)((size_t)DIM * KD / 8);
        cast_half_kernel<<<(n8 + 255) / 256, 256, 0, stream>>>(Wout, Woh, n8);
    }

    l2norm_f32_kernel<<<(MROWS * HH + 255) / 256, 256, 0, stream>>>(kf);
    l2norm_f16_kernel<<<(MROWS * HH + 255) / 256, 256, 0, stream>>>(qh);

    scan_kernel<<<BB * HH, 256, 0, stream>>>(kf, qh, vf, decayb, S0, Sq, Sout);

    out_gemm_kernel<<<dim3(8, 64), 256, 0, stream>>>(Sq, Woh, out);
}

// Round 5
// 1605.433 us; speedup vs baseline: 1.5369x; 1.5369x over previous
//
#include <hip/hip_runtime.h>

// ---------------------------------------------------------------------------
// E89 ResidualStateCell.
// Precision architecture (recurrence-critical channels get ~fp32):
//   k, v, decay  -> split-bf16 (hi+lo) MFMA GEMM, fp32 storage   [feed S]
//   q, Sq, Wout  -> fp16 (read-out only, local error ~1e-4 rel)  [don't feed S]
//   scan         -> fp32 registers, v_exp/v_rcp tanh (~1ulp), DPP reductions
// Memory plan: ws ~162 MB; q fp16 + decay live in d_out head (dead before
// the final out-GEMM overwrites it; Sout tail disjoint).
// ---------------------------------------------------------------------------

typedef __attribute__((ext_vector_type(8))) __bf16 bf16x8;
typedef __attribute__((ext_vector_type(8))) _Float16 f16x8;
typedef __attribute__((ext_vector_type(4))) float f32x4;

#define T_LEN 2048
#define BB 4
#define HH 56
#define NS 32
#define DIM 1024
#define KD 1792            // H*NS
#define MROWS 8192         // T_LEN*BB

__device__ __forceinline__ float bf2f(unsigned short u) {
    return __uint_as_float(((unsigned int)u) << 16);
}
__device__ __forceinline__ unsigned short f2bf(float f) {
    unsigned int u = __float_as_uint(f);
    u += 0x7fffu + ((u >> 16) & 1u);          // round-to-nearest-even
    return (unsigned short)(u >> 16);
}
__device__ __forceinline__ unsigned short f2h(float f) {
    union { _Float16 h; unsigned short u; } cv;
    cv.h = (_Float16)f;                       // RNE
    return cv.u;
}
__device__ __forceinline__ float h2f(unsigned short u) {
    union { unsigned short u; _Float16 h; } cv;
    cv.u = u;
    return (float)cv.h;
}

__device__ __forceinline__ float tanh_fast(float x) {
    float e = __expf(x + x);                  // exp(2x); inf-safe
    float r = __builtin_amdgcn_rcpf(e + 1.0f);
    return fmaf(-2.0f, r, 1.0f);              // 1 - 2/(1+e^{2x})
}

// Sum across each aligned group of 8 lanes, pure-VALU DPP butterfly:
// quad_perm[1,0,3,2] (xor1), quad_perm[2,3,0,1] (xor2), row_half_mirror
// (pairs each lane with the other quad of its 8-group, which holds that
// quad's full sum after the first two stages).
__device__ __forceinline__ float dpp_sum8(float x) {
    int t;
    t = __builtin_amdgcn_update_dpp(0, __float_as_int(x), 0xB1, 0xf, 0xf, true);
    x += __int_as_float(t);
    t = __builtin_amdgcn_update_dpp(0, __float_as_int(x), 0x4E, 0xf, 0xf, true);
    x += __int_as_float(t);
    t = __builtin_amdgcn_update_dpp(0, __float_as_int(x), 0x141, 0xf, 0xf, true);
    x += __int_as_float(t);
    return x;
}

__device__ __forceinline__ void gload_lds16(const void* g, void* l) {
    __builtin_amdgcn_global_load_lds(
        (const __attribute__((address_space(1))) unsigned int*)g,
        (__attribute__((address_space(3))) unsigned int*)l, 16, 0, 0);
}

// ---------------------------------------------------------------------------
// f32 -> (bf16 hi, bf16 lo) split cast, 8 elements / thread
// ---------------------------------------------------------------------------
__global__ void cast_split_kernel(const float* __restrict__ in,
                                  unsigned short* __restrict__ hi,
                                  unsigned short* __restrict__ lo, int n8) {
    int i = blockIdx.x * blockDim.x + threadIdx.x;
    if (i >= n8) return;
    const float4* p = (const float4*)in + (size_t)i * 2;
    float4 a = p[0], b = p[1];
    float xs[8] = {a.x, a.y, a.z, a.w, b.x, b.y, b.z, b.w};
    unsigned int ho[4], lv[4];
#pragma unroll
    for (int c = 0; c < 4; ++c) {
        unsigned short h0 = f2bf(xs[2 * c]);
        unsigned short h1 = f2bf(xs[2 * c + 1]);
        unsigned short l0 = f2bf(xs[2 * c] - bf2f(h0));
        unsigned short l1 = f2bf(xs[2 * c + 1] - bf2f(h1));
        ho[c] = (unsigned int)h0 | ((unsigned int)h1 << 16);
        lv[c] = (unsigned int)l0 | ((unsigned int)l1 << 16);
    }
    ((uint4*)hi)[i] = (uint4){ho[0], ho[1], ho[2], ho[3]};
    ((uint4*)lo)[i] = (uint4){lv[0], lv[1], lv[2], lv[3]};
}

// ---------------------------------------------------------------------------
// f32 -> fp16 cast, 8 elements / thread (for Wout)
// ---------------------------------------------------------------------------
__global__ void cast_half_kernel(const float* __restrict__ in,
                                 unsigned short* __restrict__ out, int n8) {
    int i = blockIdx.x * blockDim.x + threadIdx.x;
    if (i >= n8) return;
    const float4* p = (const float4*)in + (size_t)i * 2;
    float4 a = p[0], b = p[1];
    uint4 o;
    o.x = (unsigned int)f2h(a.x) | ((unsigned int)f2h(a.y) << 16);
    o.y = (unsigned int)f2h(a.z) | ((unsigned int)f2h(a.w) << 16);
    o.z = (unsigned int)f2h(b.x) | ((unsigned int)f2h(b.y) << 16);
    o.w = (unsigned int)f2h(b.z) | ((unsigned int)f2h(b.w) << 16);
    ((uint4*)out)[i] = o;
}

// ---------------------------------------------------------------------------
// Split MFMA GEMM core: Y[m,n] = sum_k A[m,k]*B[n,k], A=Ah+Al, B=Bh+Bl.
// 128x128 tile, BK=32, 256 threads = 4 waves (2x2), 16x16x32 bf16 MFMA x3.
// ---------------------------------------------------------------------------
__device__ __forceinline__ void gemm_split(
    const unsigned short* __restrict__ Ah, const unsigned short* __restrict__ Al,
    const unsigned short* __restrict__ Bh, const unsigned short* __restrict__ Bl,
    int m0, int n0, int K, int bmax,
    unsigned short* AsH, unsigned short* AsL,
    unsigned short* BsH, unsigned short* BsL,
    f32x4 (&acc)[4][4]) {
    const int tid  = threadIdx.x;
    const int lane = tid & 63;
    const int wave = tid >> 6;
    const int wm = wave >> 1, wn = wave & 1;
    const int lr = lane & 15, lkb = lane >> 4;

#pragma unroll
    for (int fr = 0; fr < 4; ++fr)
#pragma unroll
        for (int fc = 0; fc < 4; ++fc) acc[fr][fc] = (f32x4){0.f, 0.f, 0.f, 0.f};

    auto stage = [&](int kt) {
#pragma unroll
        for (int c = 0; c < 2; ++c) {
            int i = c * 256 + tid;
            int r = i >> 2, kk = (i & 3) << 3;
            size_t ao = (size_t)(m0 + r) * K + kt + kk;
            int br = n0 + r; if (br > bmax) br = bmax;
            size_t bo = (size_t)br * K + kt + kk;
            gload_lds16(Ah + ao, AsH + i * 8);
            gload_lds16(Al + ao, AsL + i * 8);
            gload_lds16(Bh + bo, BsH + i * 8);
            gload_lds16(Bl + bo, BsL + i * 8);
        }
    };

    stage(0);
    const int nk = K >> 5;
    for (int t = 0; t < nk; ++t) {
        __syncthreads();                       // drains vmcnt -> LDS tiles ready
        bf16x8 ah[4], al[4], bh[4], bl[4];
#pragma unroll
        for (int f = 0; f < 4; ++f) {
            int ai = (wm * 64 + f * 16 + lr) * 32 + lkb * 8;
            int bi = (wn * 64 + f * 16 + lr) * 32 + lkb * 8;
            ah[f] = *(const bf16x8*)(AsH + ai);
            al[f] = *(const bf16x8*)(AsL + ai);
            bh[f] = *(const bf16x8*)(BsH + bi);
            bl[f] = *(const bf16x8*)(BsL + bi);
        }
#pragma unroll
        for (int fr = 0; fr < 4; ++fr)
#pragma unroll
            for (int fc = 0; fc < 4; ++fc) {
                acc[fr][fc] = __builtin_amdgcn_mfma_f32_16x16x32_bf16(
                    ah[fr], bh[fc], acc[fr][fc], 0, 0, 0);
                acc[fr][fc] = __builtin_amdgcn_mfma_f32_16x16x32_bf16(
                    ah[fr], bl[fc], acc[fr][fc], 0, 0, 0);
                acc[fr][fc] = __builtin_amdgcn_mfma_f32_16x16x32_bf16(
                    al[fr], bh[fc], acc[fr][fc], 0, 0, 0);
            }
        __syncthreads();                       // all waves done reading LDS
        if (t + 1 < nk) stage((t + 1) << 5);
    }
}

// ---------------------------------------------------------------------------
// Projection GEMM over x (M=8192, K=1024).
// mode 0: silu -> fp32 dstF   (k, v — recurrence-critical)
// mode 1: silu -> fp16 dstH   (q — read-out only)
// mode 2: decay computation -> fp32 decayb (n < 56)
// ---------------------------------------------------------------------------
__global__ __launch_bounds__(256) void proj_gemm_kernel(
    const unsigned short* __restrict__ xh, const unsigned short* __restrict__ xl,
    const unsigned short* __restrict__ Bh, const unsigned short* __restrict__ Bl,
    const float* __restrict__ A_log, const float* __restrict__ dt_bias,
    float* __restrict__ dstF, unsigned short* __restrict__ dstH,
    float* __restrict__ decayb, int mode) {
    __shared__ __align__(16) unsigned short AsH[128 * 32];
    __shared__ __align__(16) unsigned short AsL[128 * 32];
    __shared__ __align__(16) unsigned short BsH[128 * 32];
    __shared__ __align__(16) unsigned short BsL[128 * 32];

    int m0 = blockIdx.y * 128;
    int n0 = blockIdx.x * 128;
    int bmax = (mode == 2) ? (HH - 1) : (KD - 1);

    f32x4 acc[4][4];
    gemm_split(xh, xl, Bh, Bl, m0, n0, DIM, bmax, AsH, AsL, BsH, BsL, acc);

    const int lane = threadIdx.x & 63, wave = threadIdx.x >> 6;
    const int wm = wave >> 1, wn = wave & 1, lr = lane & 15, lkb = lane >> 4;

#pragma unroll
    for (int fr = 0; fr < 4; ++fr)
#pragma unroll
        for (int fc = 0; fc < 4; ++fc)
#pragma unroll
            for (int v = 0; v < 4; ++v) {
                int m = m0 + wm * 64 + fr * 16 + lkb * 4 + v;
                int n = n0 + wn * 64 + fc * 16 + lr;
                float y = acc[fr][fc][v];
                if (mode == 0) {
                    float s = y / (1.f + __expf(-y));          // silu
                    dstF[(size_t)m * KD + n] = s;
                } else if (mode == 1) {
                    float s = y / (1.f + __expf(-y));
                    dstH[(size_t)m * KD + n] = f2h(s);
                } else if (n < HH) {
                    float z = y + dt_bias[n];
                    float sp = (z > 20.f) ? z : log1pf(__expf(z));   // softplus
                    decayb[(size_t)m * HH + n] = __expf(-__expf(A_log[n]) * sp);
                }
            }
}

// ---------------------------------------------------------------------------
// Output GEMM (fp16): out = Sq @ Wout^T, f32 store.
// ---------------------------------------------------------------------------
__global__ __launch_bounds__(256) void out_gemm_kernel(
    const unsigned short* __restrict__ Sq, const unsigned short* __restrict__ Wo,
    float* __restrict__ out) {
    __shared__ __align__(16) unsigned short As[128 * 32];
    __shared__ __align__(16) unsigned short Bs[128 * 32];
    int m0 = blockIdx.y * 128, n0 = blockIdx.x * 128;

    const int tid  = threadIdx.x;
    const int lane = tid & 63;
    const int wave = tid >> 6;
    const int wm = wave >> 1, wn = wave & 1;
    const int lr = lane & 15, lkb = lane >> 4;

    f32x4 acc[4][4];
#pragma unroll
    for (int fr = 0; fr < 4; ++fr)
#pragma unroll
        for (int fc = 0; fc < 4; ++fc) acc[fr][fc] = (f32x4){0.f, 0.f, 0.f, 0.f};

    auto stage = [&](int kt) {
#pragma unroll
        for (int c = 0; c < 2; ++c) {
            int i = c * 256 + tid;
            int r = i >> 2, kk = (i & 3) << 3;
            gload_lds16(Sq + (size_t)(m0 + r) * KD + kt + kk, As + i * 8);
            gload_lds16(Wo + (size_t)(n0 + r) * KD + kt + kk, Bs + i * 8);
        }
    };

    stage(0);
    const int nk = KD >> 5;
    for (int t = 0; t < nk; ++t) {
        __syncthreads();
        f16x8 af[4], bf[4];
#pragma unroll
        for (int f = 0; f < 4; ++f) {
            af[f] = *(const f16x8*)(As + (wm * 64 + f * 16 + lr) * 32 + lkb * 8);
            bf[f] = *(const f16x8*)(Bs + (wn * 64 + f * 16 + lr) * 32 + lkb * 8);
        }
#pragma unroll
        for (int fr = 0; fr < 4; ++fr)
#pragma unroll
            for (int fc = 0; fc < 4; ++fc)
                acc[fr][fc] = __builtin_amdgcn_mfma_f32_16x16x32_f16(
                    af[fr], bf[fc], acc[fr][fc], 0, 0, 0);
        __syncthreads();
        if (t + 1 < nk) stage((t + 1) << 5);
    }

#pragma unroll
    for (int fr = 0; fr < 4; ++fr)
#pragma unroll
        for (int fc = 0; fc < 4; ++fc)
#pragma unroll
            for (int v = 0; v < 4; ++v) {
                int m = m0 + wm * 64 + fr * 16 + lkb * 4 + v;
                int n = n0 + wn * 64 + fc * 16 + lr;
                out[(size_t)m * DIM + n] = acc[fr][fc][v];
            }
}

// ---------------------------------------------------------------------------
// L2 normalization over NS=32: fp32 buffer (k).
// ---------------------------------------------------------------------------
__global__ void l2norm_f32_kernel(float* __restrict__ buf) {
    int g = blockIdx.x * blockDim.x + threadIdx.x;
    const int NG = MROWS * HH;
    if (g >= NG) return;
    int row = g / HH, hh = g - row * HH;
    float* p = buf + (size_t)row * KD + hh * NS;

    float4 u[8];
#pragma unroll
    for (int c = 0; c < 8; ++c) u[c] = ((const float4*)p)[c];
    float ss = 0.f;
#pragma unroll
    for (int c = 0; c < 8; ++c) {
        ss = fmaf(u[c].x, u[c].x, ss); ss = fmaf(u[c].y, u[c].y, ss);
        ss = fmaf(u[c].z, u[c].z, ss); ss = fmaf(u[c].w, u[c].w, ss);
    }
    float sc = 1.f / fmaxf(sqrtf(ss), 1e-12f);
#pragma unroll
    for (int c = 0; c < 8; ++c) {
        u[c].x *= sc; u[c].y *= sc; u[c].z *= sc; u[c].w *= sc;
        ((float4*)p)[c] = u[c];
    }
}

// ---------------------------------------------------------------------------
// L2 normalization over NS=32: fp16 buffer (q), fp32 math.
// ---------------------------------------------------------------------------
__global__ void l2norm_f16_kernel(unsigned short* __restrict__ buf) {
    int g = blockIdx.x * blockDim.x + threadIdx.x;
    const int NG = MROWS * HH;
    if (g >= NG) return;
    int row = g / HH, hh = g - row * HH;
    unsigned short* p = buf + (size_t)row * KD + hh * NS;

    uint4 u[4];
#pragma unroll
    for (int c = 0; c < 4; ++c) u[c] = ((const uint4*)p)[c];
    float ss = 0.f;
    auto acc2 = [&](unsigned int w) {
        float a = h2f((unsigned short)(w & 0xffff));
        float b = h2f((unsigned short)(w >> 16));
        ss = fmaf(a, a, ss); ss = fmaf(b, b, ss);
    };
#pragma unroll
    for (int c = 0; c < 4; ++c) { acc2(u[c].x); acc2(u[c].y); acc2(u[c].z); acc2(u[c].w); }
    float sc = 1.f / fmaxf(sqrtf(ss), 1e-12f);
    auto scl = [&](unsigned int w) -> unsigned int {
        unsigned int lo = f2h(h2f((unsigned short)(w & 0xffff)) * sc);
        unsigned int hi = f2h(h2f((unsigned short)(w >> 16)) * sc);
        return lo | (hi << 16);
    };
#pragma unroll
    for (int c = 0; c < 4; ++c) {
        u[c].x = scl(u[c].x); u[c].y = scl(u[c].y);
        u[c].z = scl(u[c].z); u[c].w = scl(u[c].w);
        ((uint4*)p)[c] = u[c];
    }
}

// ---------------------------------------------------------------------------
// Sequential scan (fp32 math; k,v,decay fp32; q fp16). One block per (b,h);
// 8 lanes per state column j, 4 state elements per lane. Prefetch 8 ahead.
// Reductions via DPP (VALU-only), tanh via v_exp+v_rcp.
// ---------------------------------------------------------------------------
__global__ __launch_bounds__(256) void scan_kernel(
    const float* __restrict__ kf, const unsigned short* __restrict__ qh,
    const float* __restrict__ vf, const float* __restrict__ decayb,
    const float* __restrict__ S0, unsigned short* __restrict__ Sq,
    float* __restrict__ Sout) {
    const int bh = blockIdx.x;                 // 0..223
    const int b = bh / HH, h = bh - b * HH;
    const int tid = threadIdx.x;
    const int j = tid >> 3, sub = tid & 7, i0 = sub << 2;

    const float* Sp = S0 + (size_t)bh * NS * NS;
    float s0 = Sp[(i0 + 0) * NS + j];
    float s1 = Sp[(i0 + 1) * NS + j];
    float s2 = Sp[(i0 + 2) * NS + j];
    float s3 = Sp[(i0 + 3) * NS + j];

    const size_t cb = (size_t)h * NS;
    constexpr int PF = 8;
    float4 kp[PF]; uint2 qp[PF]; float vp[PF], dp[PF];

#define LOADS(t, K_, Q_, V_, D_)                                   \
    {                                                              \
        size_t ro = ((size_t)(t) * BB + b) * KD + cb;              \
        K_ = *(const float4*)(kf + ro + i0);                       \
        Q_ = *(const uint2*)(qh + ro + i0);                        \
        V_ = vf[ro + j];                                           \
        D_ = decayb[((size_t)(t) * BB + b) * HH + h];              \
    }

#pragma unroll
    for (int p = 0; p < PF; ++p) { LOADS(p, kp[p], qp[p], vp[p], dp[p]); }

    for (int tb = 0; tb < T_LEN; tb += PF) {
#pragma unroll
        for (int p = 0; p < PF; ++p) {
            const int t = tb + p;
            float k0 = kp[p].x, k1 = kp[p].y, k2 = kp[p].z, k3 = kp[p].w;
            float q0 = h2f((unsigned short)(qp[p].x & 0xffff));
            float q1 = h2f((unsigned short)(qp[p].x >> 16));
            float q2 = h2f((unsigned short)(qp[p].y & 0xffff));
            float q3 = h2f((unsigned short)(qp[p].y >> 16));
            float vj = vp[p];
            float d  = dp[p];
            if (t + PF < T_LEN) { LOADS(t + PF, kp[p], qp[p], vp[p], dp[p]); }

            // retrieved_j = sum_i S[i][j]*k_i  (tree partial + DPP 8-lane sum)
            float r = fmaf(k1, s1, k0 * s0) + fmaf(k3, s3, k2 * s2);
            r = dpp_sum8(r);
            float delta = vj - r;

            float a0 = fmaf(d, s0, k0 * delta);
            float a1 = fmaf(d, s1, k1 * delta);
            float a2 = fmaf(d, s2, k2 * delta);
            float a3 = fmaf(d, s3, k3 * delta);
            s0 += tanh_fast(a0); s1 += tanh_fast(a1);
            s2 += tanh_fast(a2); s3 += tanh_fast(a3);

            // Sq_j = sum_i S[i][j]*q_i
            float o = fmaf(q1, s1, q0 * s0) + fmaf(q3, s3, q2 * s2);
            o = dpp_sum8(o);
            if (sub == 0) {
                size_t ro = ((size_t)t * BB + b) * KD + cb;
                Sq[ro + j] = f2h(o);
            }
        }
    }
#undef LOADS

    float* so = Sout + (size_t)bh * NS * NS;
    so[(i0 + 0) * NS + j] = s0;
    so[(i0 + 1) * NS + j] = s1;
    so[(i0 + 2) * NS + j] = s2;
    so[(i0 + 3) * NS + j] = s3;
}

// ---------------------------------------------------------------------------
extern "C" void kernel_launch(void* const* d_in, const int* in_sizes, int n_in,
                              void* d_out, int out_size, void* d_ws, size_t ws_size,
                              hipStream_t stream) {
    const float* x       = (const float*)d_in[0];
    const float* S0      = (const float*)d_in[1];
    const float* Wq      = (const float*)d_in[2];
    const float* Wk      = (const float*)d_in[3];
    const float* Wv      = (const float*)d_in[4];
    const float* Wa      = (const float*)d_in[5];
    const float* A_log   = (const float*)d_in[6];
    const float* dt_bias = (const float*)d_in[7];
    const float* Wout    = (const float*)d_in[8];

    float* out  = (float*)d_out;
    float* Sout = out + (size_t)T_LEN * BB * DIM;

    // --- workspace layout (~162 MB peak) ---
    char* w = (char*)d_ws;
    auto alloc = [&](size_t bytes) {
        char* p = w; w += (bytes + 255) & ~(size_t)255; return p;
    };
    unsigned short* xh  = (unsigned short*)alloc((size_t)MROWS * DIM * 2);  // 16.8 MB
    unsigned short* xl  = (unsigned short*)alloc((size_t)MROWS * DIM * 2);  // 16.8 MB
    unsigned short* Wbh = (unsigned short*)alloc((size_t)KD * DIM * 2);     // 3.67 MB (reused)
    unsigned short* Wbl = (unsigned short*)alloc((size_t)KD * DIM * 2);     // 3.67 MB (reused)
    float* kf           = (float*)alloc((size_t)MROWS * KD * 4);            // 58.7 MB
    float* vf           = (float*)alloc((size_t)MROWS * KD * 4);            // 58.7 MB
    unsigned short* Woh = (unsigned short*)alloc((size_t)DIM * KD * 2);     // 3.67 MB
    // Sq (fp16, 29.4 MB) aliases xh+xl (33.6 MB): x dead after last proj GEMM.
    unsigned short* Sq  = xh;

    // --- d_out head as scratch for q (fp16) + decay: dead before out GEMM ---
    unsigned short* qh  = (unsigned short*)d_out;                 // 29.36 MB
    float* decayb       = (float*)((char*)d_out + (size_t)MROWS * KD * 2); // 1.83 MB
    // (29.36 + 1.83 = 31.2 MB <= 33.55 MB out region; Sout at tail is disjoint)

    auto casts = [&](const float* src, unsigned short* hi, unsigned short* lo, size_t n) {
        int n8 = (int)(n / 8);
        cast_split_kernel<<<(n8 + 255) / 256, 256, 0, stream>>>(src, hi, lo, n8);
    };

    casts(x, xh, xl, (size_t)MROWS * DIM);

    // k projection -> fp32
    casts(Wk, Wbh, Wbl, (size_t)KD * DIM);
    proj_gemm_kernel<<<dim3(14, 64), 256, 0, stream>>>(
        xh, xl, Wbh, Wbl, A_log, dt_bias, kf, nullptr, nullptr, 0);
    // v projection -> fp32
    casts(Wv, Wbh, Wbl, (size_t)KD * DIM);
    proj_gemm_kernel<<<dim3(14, 64), 256, 0, stream>>>(
        xh, xl, Wbh, Wbl, A_log, dt_bias, vf, nullptr, nullptr, 0);
    // q projection -> fp16 (d_out scratch)
    casts(Wq, Wbh, Wbl, (size_t)KD * DIM);
    proj_gemm_kernel<<<dim3(14, 64), 256, 0, stream>>>(
        xh, xl, Wbh, Wbl, A_log, dt_bias, nullptr, qh, nullptr, 1);
    // decay -> fp32 (d_out scratch)
    casts(Wa, Wbh, Wbl, (size_t)HH * DIM);
    proj_gemm_kernel<<<dim3(1, 64), 256, 0, stream>>>(
        xh, xl, Wbh, Wbl, A_log, dt_bias, nullptr, nullptr, decayb, 2);

    // Wout -> fp16
    {
        int n8 = (int)((size_t)DIM * KD / 8);
        cast_half_kernel<<<(n8 + 255) / 256, 256, 0, stream>>>(Wout, Woh, n8);
    }

    l2norm_f32_kernel<<<(MROWS * HH + 255) / 256, 256, 0, stream>>>(kf);
    l2norm_f16_kernel<<<(MROWS * HH + 255) / 256, 256, 0, stream>>>(qh);

    scan_kernel<<<BB * HH, 256, 0, stream>>>(kf, qh, vf, decayb, S0, Sq, Sout);

    out_gemm_kernel<<<dim3(8, 64), 256, 0, stream>>>(Sq, Woh, out);
}

// Round 6
// 1426.268 us; speedup vs baseline: 1.7300x; 1.1256x over previous
//
#include <hip/hip_runtime.h>

// ---------------------------------------------------------------------------
// E89 ResidualStateCell.
// Precision architecture (recurrence-critical channels get ~fp32):
//   k, v, decay  -> split-bf16 (hi+lo) MFMA GEMM, fp32 storage   [feed S]
//   q, Sq, Wout  -> fp16 (read-out only, local error ~1e-4 rel)  [don't feed S]
//   scan         -> fp32 registers, v_exp/v_rcp tanh (~1ulp), DPP reductions
// Layout: scan operands k,v,q stored TRANSPOSED [B][H][T][NS] (decay [B][H][T])
// so each scan block streams contiguously (324 B/step sequential) instead of
// 28.7 KB-strided hops. Sq stays [T][B][KD] for the unchanged out-GEMM.
// Memory plan: ws ~162 MB; q fp16 + decay live in d_out head (dead before
// the final out-GEMM overwrites it; Sout tail disjoint).
// ---------------------------------------------------------------------------

typedef __attribute__((ext_vector_type(8))) __bf16 bf16x8;
typedef __attribute__((ext_vector_type(8))) _Float16 f16x8;
typedef __attribute__((ext_vector_type(4))) float f32x4;

#define T_LEN 2048
#define BB 4
#define HH 56
#define NS 32
#define DIM 1024
#define KD 1792            // H*NS
#define MROWS 8192         // T_LEN*BB

__device__ __forceinline__ float bf2f(unsigned short u) {
    return __uint_as_float(((unsigned int)u) << 16);
}
__device__ __forceinline__ unsigned short f2bf(float f) {
    unsigned int u = __float_as_uint(f);
    u += 0x7fffu + ((u >> 16) & 1u);          // round-to-nearest-even
    return (unsigned short)(u >> 16);
}
__device__ __forceinline__ unsigned short f2h(float f) {
    union { _Float16 h; unsigned short u; } cv;
    cv.h = (_Float16)f;                       // RNE
    return cv.u;
}
__device__ __forceinline__ float h2f(unsigned short u) {
    union { unsigned short u; _Float16 h; } cv;
    cv.u = u;
    return (float)cv.h;
}

// tanh via v_exp_f32 (2^x) directly: tanh(x) = 1 - 2/(1+2^(2*log2e*x))
__device__ __forceinline__ float tanh_fast(float x) {
    float e = __builtin_amdgcn_exp2f(x * 2.885390081777927f);
    float r = __builtin_amdgcn_rcpf(e + 1.0f);
    return fmaf(-2.0f, r, 1.0f);
}

// Sum across each aligned group of 8 lanes, pure-VALU DPP butterfly.
__device__ __forceinline__ float dpp_sum8(float x) {
    int t;
    t = __builtin_amdgcn_update_dpp(0, __float_as_int(x), 0xB1, 0xf, 0xf, true);
    x += __int_as_float(t);
    t = __builtin_amdgcn_update_dpp(0, __float_as_int(x), 0x4E, 0xf, 0xf, true);
    x += __int_as_float(t);
    t = __builtin_amdgcn_update_dpp(0, __float_as_int(x), 0x141, 0xf, 0xf, true);
    x += __int_as_float(t);
    return x;
}

__device__ __forceinline__ void gload_lds16(const void* g, void* l) {
    __builtin_amdgcn_global_load_lds(
        (const __attribute__((address_space(1))) unsigned int*)g,
        (__attribute__((address_space(3))) unsigned int*)l, 16, 0, 0);
}

// ---------------------------------------------------------------------------
// f32 -> (bf16 hi, bf16 lo) split cast, 8 elements / thread
// ---------------------------------------------------------------------------
__global__ void cast_split_kernel(const float* __restrict__ in,
                                  unsigned short* __restrict__ hi,
                                  unsigned short* __restrict__ lo, int n8) {
    int i = blockIdx.x * blockDim.x + threadIdx.x;
    if (i >= n8) return;
    const float4* p = (const float4*)in + (size_t)i * 2;
    float4 a = p[0], b = p[1];
    float xs[8] = {a.x, a.y, a.z, a.w, b.x, b.y, b.z, b.w};
    unsigned int ho[4], lv[4];
#pragma unroll
    for (int c = 0; c < 4; ++c) {
        unsigned short h0 = f2bf(xs[2 * c]);
        unsigned short h1 = f2bf(xs[2 * c + 1]);
        unsigned short l0 = f2bf(xs[2 * c] - bf2f(h0));
        unsigned short l1 = f2bf(xs[2 * c + 1] - bf2f(h1));
        ho[c] = (unsigned int)h0 | ((unsigned int)h1 << 16);
        lv[c] = (unsigned int)l0 | ((unsigned int)l1 << 16);
    }
    ((uint4*)hi)[i] = (uint4){ho[0], ho[1], ho[2], ho[3]};
    ((uint4*)lo)[i] = (uint4){lv[0], lv[1], lv[2], lv[3]};
}

// ---------------------------------------------------------------------------
// f32 -> fp16 cast, 8 elements / thread (for Wout)
// ---------------------------------------------------------------------------
__global__ void cast_half_kernel(const float* __restrict__ in,
                                 unsigned short* __restrict__ out, int n8) {
    int i = blockIdx.x * blockDim.x + threadIdx.x;
    if (i >= n8) return;
    const float4* p = (const float4*)in + (size_t)i * 2;
    float4 a = p[0], b = p[1];
    uint4 o;
    o.x = (unsigned int)f2h(a.x) | ((unsigned int)f2h(a.y) << 16);
    o.y = (unsigned int)f2h(a.z) | ((unsigned int)f2h(a.w) << 16);
    o.z = (unsigned int)f2h(b.x) | ((unsigned int)f2h(b.y) << 16);
    o.w = (unsigned int)f2h(b.z) | ((unsigned int)f2h(b.w) << 16);
    ((uint4*)out)[i] = o;
}

// ---------------------------------------------------------------------------
// Split MFMA GEMM core: Y[m,n] = sum_k A[m,k]*B[n,k], A=Ah+Al, B=Bh+Bl.
// 128x128 tile, BK=32, 256 threads = 4 waves (2x2), 16x16x32 bf16 MFMA x3.
// ---------------------------------------------------------------------------
__device__ __forceinline__ void gemm_split(
    const unsigned short* __restrict__ Ah, const unsigned short* __restrict__ Al,
    const unsigned short* __restrict__ Bh, const unsigned short* __restrict__ Bl,
    int m0, int n0, int K, int bmax,
    unsigned short* AsH, unsigned short* AsL,
    unsigned short* BsH, unsigned short* BsL,
    f32x4 (&acc)[4][4]) {
    const int tid  = threadIdx.x;
    const int lane = tid & 63;
    const int wave = tid >> 6;
    const int wm = wave >> 1, wn = wave & 1;
    const int lr = lane & 15, lkb = lane >> 4;

#pragma unroll
    for (int fr = 0; fr < 4; ++fr)
#pragma unroll
        for (int fc = 0; fc < 4; ++fc) acc[fr][fc] = (f32x4){0.f, 0.f, 0.f, 0.f};

    auto stage = [&](int kt) {
#pragma unroll
        for (int c = 0; c < 2; ++c) {
            int i = c * 256 + tid;
            int r = i >> 2, kk = (i & 3) << 3;
            size_t ao = (size_t)(m0 + r) * K + kt + kk;
            int br = n0 + r; if (br > bmax) br = bmax;
            size_t bo = (size_t)br * K + kt + kk;
            gload_lds16(Ah + ao, AsH + i * 8);
            gload_lds16(Al + ao, AsL + i * 8);
            gload_lds16(Bh + bo, BsH + i * 8);
            gload_lds16(Bl + bo, BsL + i * 8);
        }
    };

    stage(0);
    const int nk = K >> 5;
    for (int t = 0; t < nk; ++t) {
        __syncthreads();                       // drains vmcnt -> LDS tiles ready
        bf16x8 ah[4], al[4], bh[4], bl[4];
#pragma unroll
        for (int f = 0; f < 4; ++f) {
            int ai = (wm * 64 + f * 16 + lr) * 32 + lkb * 8;
            int bi = (wn * 64 + f * 16 + lr) * 32 + lkb * 8;
            ah[f] = *(const bf16x8*)(AsH + ai);
            al[f] = *(const bf16x8*)(AsL + ai);
            bh[f] = *(const bf16x8*)(BsH + bi);
            bl[f] = *(const bf16x8*)(BsL + bi);
        }
#pragma unroll
        for (int fr = 0; fr < 4; ++fr)
#pragma unroll
            for (int fc = 0; fc < 4; ++fc) {
                acc[fr][fc] = __builtin_amdgcn_mfma_f32_16x16x32_bf16(
                    ah[fr], bh[fc], acc[fr][fc], 0, 0, 0);
                acc[fr][fc] = __builtin_amdgcn_mfma_f32_16x16x32_bf16(
                    ah[fr], bl[fc], acc[fr][fc], 0, 0, 0);
                acc[fr][fc] = __builtin_amdgcn_mfma_f32_16x16x32_bf16(
                    al[fr], bh[fc], acc[fr][fc], 0, 0, 0);
            }
        __syncthreads();                       // all waves done reading LDS
        if (t + 1 < nk) stage((t + 1) << 5);
    }
}

// ---------------------------------------------------------------------------
// Projection GEMM over x (M=8192, K=1024).  Row m = t*BB + b.
// mode 0: silu -> fp32 dstF at [B][H][T][NS]     (k, v — recurrence-critical)
// mode 1: silu -> fp16 dstH at [B][H][T][NS]     (q — read-out only)
// mode 2: decay -> fp32 decayb at [B][H][T]      (n < 56)
// ---------------------------------------------------------------------------
__global__ __launch_bounds__(256) void proj_gemm_kernel(
    const unsigned short* __restrict__ xh, const unsigned short* __restrict__ xl,
    const unsigned short* __restrict__ Bh, const unsigned short* __restrict__ Bl,
    const float* __restrict__ A_log, const float* __restrict__ dt_bias,
    float* __restrict__ dstF, unsigned short* __restrict__ dstH,
    float* __restrict__ decayb, int mode) {
    __shared__ __align__(16) unsigned short AsH[128 * 32];
    __shared__ __align__(16) unsigned short AsL[128 * 32];
    __shared__ __align__(16) unsigned short BsH[128 * 32];
    __shared__ __align__(16) unsigned short BsL[128 * 32];

    int m0 = blockIdx.y * 128;
    int n0 = blockIdx.x * 128;
    int bmax = (mode == 2) ? (HH - 1) : (KD - 1);

    f32x4 acc[4][4];
    gemm_split(xh, xl, Bh, Bl, m0, n0, DIM, bmax, AsH, AsL, BsH, BsL, acc);

    const int lane = threadIdx.x & 63, wave = threadIdx.x >> 6;
    const int wm = wave >> 1, wn = wave & 1, lr = lane & 15, lkb = lane >> 4;

#pragma unroll
    for (int fr = 0; fr < 4; ++fr)
#pragma unroll
        for (int fc = 0; fc < 4; ++fc)
#pragma unroll
            for (int v = 0; v < 4; ++v) {
                int m = m0 + wm * 64 + fr * 16 + lkb * 4 + v;   // m = t*4 + b
                int n = n0 + wn * 64 + fc * 16 + lr;
                int t = m >> 2, b = m & 3;
                float y = acc[fr][fc][v];
                if (mode == 0) {
                    int h = n >> 5, i = n & 31;
                    float s = y / (1.f + __expf(-y));          // silu
                    dstF[(((size_t)(b * HH + h)) * T_LEN + t) * NS + i] = s;
                } else if (mode == 1) {
                    int h = n >> 5, i = n & 31;
                    float s = y / (1.f + __expf(-y));
                    dstH[(((size_t)(b * HH + h)) * T_LEN + t) * NS + i] = f2h(s);
                } else if (n < HH) {
                    float z = y + dt_bias[n];
                    float sp = (z > 20.f) ? z : log1pf(__expf(z));   // softplus
                    decayb[((size_t)(b * HH + n)) * T_LEN + t] =
                        __expf(-__expf(A_log[n]) * sp);
                }
            }
}

// ---------------------------------------------------------------------------
// Output GEMM (fp16): out = Sq @ Wout^T, f32 store.
// ---------------------------------------------------------------------------
__global__ __launch_bounds__(256) void out_gemm_kernel(
    const unsigned short* __restrict__ Sq, const unsigned short* __restrict__ Wo,
    float* __restrict__ out) {
    __shared__ __align__(16) unsigned short As[128 * 32];
    __shared__ __align__(16) unsigned short Bs[128 * 32];
    int m0 = blockIdx.y * 128, n0 = blockIdx.x * 128;

    const int tid  = threadIdx.x;
    const int lane = tid & 63;
    const int wave = tid >> 6;
    const int wm = wave >> 1, wn = wave & 1;
    const int lr = lane & 15, lkb = lane >> 4;

    f32x4 acc[4][4];
#pragma unroll
    for (int fr = 0; fr < 4; ++fr)
#pragma unroll
        for (int fc = 0; fc < 4; ++fc) acc[fr][fc] = (f32x4){0.f, 0.f, 0.f, 0.f};

    auto stage = [&](int kt) {
#pragma unroll
        for (int c = 0; c < 2; ++c) {
            int i = c * 256 + tid;
            int r = i >> 2, kk = (i & 3) << 3;
            gload_lds16(Sq + (size_t)(m0 + r) * KD + kt + kk, As + i * 8);
            gload_lds16(Wo + (size_t)(n0 + r) * KD + kt + kk, Bs + i * 8);
        }
    };

    stage(0);
    const int nk = KD >> 5;
    for (int t = 0; t < nk; ++t) {
        __syncthreads();
        f16x8 af[4], bf[4];
#pragma unroll
        for (int f = 0; f < 4; ++f) {
            af[f] = *(const f16x8*)(As + (wm * 64 + f * 16 + lr) * 32 + lkb * 8);
            bf[f] = *(const f16x8*)(Bs + (wn * 64 + f * 16 + lr) * 32 + lkb * 8);
        }
#pragma unroll
        for (int fr = 0; fr < 4; ++fr)
#pragma unroll
            for (int fc = 0; fc < 4; ++fc)
                acc[fr][fc] = __builtin_amdgcn_mfma_f32_16x16x32_f16(
                    af[fr], bf[fc], acc[fr][fc], 0, 0, 0);
        __syncthreads();
        if (t + 1 < nk) stage((t + 1) << 5);
    }

#pragma unroll
    for (int fr = 0; fr < 4; ++fr)
#pragma unroll
        for (int fc = 0; fc < 4; ++fc)
#pragma unroll
            for (int v = 0; v < 4; ++v) {
                int m = m0 + wm * 64 + fr * 16 + lkb * 4 + v;
                int n = n0 + wn * 64 + fc * 16 + lr;
                out[(size_t)m * DIM + n] = acc[fr][fc][v];
            }
}

// ---------------------------------------------------------------------------
// L2 normalization over NS=32 (transposed layout: rows contiguous).
// ---------------------------------------------------------------------------
__global__ void l2norm_f32_kernel(float* __restrict__ buf) {
    int g = blockIdx.x * blockDim.x + threadIdx.x;
    const int NG = MROWS * HH;
    if (g >= NG) return;
    float* p = buf + (size_t)g * NS;

    float4 u[8];
#pragma unroll
    for (int c = 0; c < 8; ++c) u[c] = ((const float4*)p)[c];
    float ss = 0.f;
#pragma unroll
    for (int c = 0; c < 8; ++c) {
        ss = fmaf(u[c].x, u[c].x, ss); ss = fmaf(u[c].y, u[c].y, ss);
        ss = fmaf(u[c].z, u[c].z, ss); ss = fmaf(u[c].w, u[c].w, ss);
    }
    float sc = 1.f / fmaxf(sqrtf(ss), 1e-12f);
#pragma unroll
    for (int c = 0; c < 8; ++c) {
        u[c].x *= sc; u[c].y *= sc; u[c].z *= sc; u[c].w *= sc;
        ((float4*)p)[c] = u[c];
    }
}

__global__ void l2norm_f16_kernel(unsigned short* __restrict__ buf) {
    int g = blockIdx.x * blockDim.x + threadIdx.x;
    const int NG = MROWS * HH;
    if (g >= NG) return;
    unsigned short* p = buf + (size_t)g * NS;

    uint4 u[4];
#pragma unroll
    for (int c = 0; c < 4; ++c) u[c] = ((const uint4*)p)[c];
    float ss = 0.f;
    auto acc2 = [&](unsigned int w) {
        float a = h2f((unsigned short)(w & 0xffff));
        float b = h2f((unsigned short)(w >> 16));
        ss = fmaf(a, a, ss); ss = fmaf(b, b, ss);
    };
#pragma unroll
    for (int c = 0; c < 4; ++c) { acc2(u[c].x); acc2(u[c].y); acc2(u[c].z); acc2(u[c].w); }
    float sc = 1.f / fmaxf(sqrtf(ss), 1e-12f);
    auto scl = [&](unsigned int w) -> unsigned int {
        unsigned int lo = f2h(h2f((unsigned short)(w & 0xffff)) * sc);
        unsigned int hi = f2h(h2f((unsigned short)(w >> 16)) * sc);
        return lo | (hi << 16);
    };
#pragma unroll
    for (int c = 0; c < 4; ++c) {
        u[c].x = scl(u[c].x); u[c].y = scl(u[c].y);
        u[c].z = scl(u[c].z); u[c].w = scl(u[c].w);
        ((uint4*)p)[c] = u[c];
    }
}

// ---------------------------------------------------------------------------
// Sequential scan (fp32 math; k,v,decay fp32; q fp16), transposed inputs:
// block bh streams k/v/q at [bh][t][NS] (contiguous 324 B/step) and decay at
// [bh][t]. 8 lanes per state column j, 4 state elements per lane. Prefetch 8.
// Sq written in [T][B][KD] for the unchanged out-GEMM.
// ---------------------------------------------------------------------------
__global__ __launch_bounds__(256) void scan_kernel(
    const float* __restrict__ kf, const unsigned short* __restrict__ qh,
    const float* __restrict__ vf, const float* __restrict__ decayb,
    const float* __restrict__ S0, unsigned short* __restrict__ Sq,
    float* __restrict__ Sout) {
    const int bh = blockIdx.x;                 // 0..223  (= b*HH + h)
    const int b = bh / HH, h = bh - b * HH;
    const int tid = threadIdx.x;
    const int j = tid >> 3, sub = tid & 7, i0 = sub << 2;

    const float* Sp = S0 + (size_t)bh * NS * NS;
    float s0 = Sp[(i0 + 0) * NS + j];
    float s1 = Sp[(i0 + 1) * NS + j];
    float s2 = Sp[(i0 + 2) * NS + j];
    float s3 = Sp[(i0 + 3) * NS + j];

    const size_t base  = (size_t)bh * T_LEN * NS;
    const size_t dbase = (size_t)bh * T_LEN;
    const size_t cb    = (size_t)h * NS;
    constexpr int PF = 8;
    float4 kp[PF]; uint2 qp[PF]; float vp[PF], dp[PF];

#define LOADS(t, K_, Q_, V_, D_)                                   \
    {                                                              \
        size_t eo = base + (size_t)(t) * NS;                       \
        K_ = *(const float4*)(kf + eo + i0);                       \
        Q_ = *(const uint2*)(qh + eo + i0);                        \
        V_ = vf[eo + j];                                           \
        D_ = decayb[dbase + (t)];                                  \
    }

#pragma unroll
    for (int p = 0; p < PF; ++p) { LOADS(p, kp[p], qp[p], vp[p], dp[p]); }

    for (int tb = 0; tb < T_LEN; tb += PF) {
#pragma unroll
        for (int p = 0; p < PF; ++p) {
            const int t = tb + p;
            float k0 = kp[p].x, k1 = kp[p].y, k2 = kp[p].z, k3 = kp[p].w;
            float q0 = h2f((unsigned short)(qp[p].x & 0xffff));
            float q1 = h2f((unsigned short)(qp[p].x >> 16));
            float q2 = h2f((unsigned short)(qp[p].y & 0xffff));
            float q3 = h2f((unsigned short)(qp[p].y >> 16));
            float vj = vp[p];
            float d  = dp[p];
            if (t + PF < T_LEN) { LOADS(t + PF, kp[p], qp[p], vp[p], dp[p]); }

            // retrieved_j = sum_i S[i][j]*k_i  (tree partial + DPP 8-lane sum)
            float r = fmaf(k1, s1, k0 * s0) + fmaf(k3, s3, k2 * s2);
            r = dpp_sum8(r);
            float delta = vj - r;

            float a0 = fmaf(d, s0, k0 * delta);
            float a1 = fmaf(d, s1, k1 * delta);
            float a2 = fmaf(d, s2, k2 * delta);
            float a3 = fmaf(d, s3, k3 * delta);
            s0 += tanh_fast(a0); s1 += tanh_fast(a1);
            s2 += tanh_fast(a2); s3 += tanh_fast(a3);

            // Sq_j = sum_i S[i][j]*q_i
            float o = fmaf(q1, s1, q0 * s0) + fmaf(q3, s3, q2 * s2);
            o = dpp_sum8(o);
            if (sub == 0) {
                size_t ro = ((size_t)t * BB + b) * KD + cb;
                Sq[ro + j] = f2h(o);
            }
        }
    }
#undef LOADS

    float* so = Sout + (size_t)bh * NS * NS;
    so[(i0 + 0) * NS + j] = s0;
    so[(i0 + 1) * NS + j] = s1;
    so[(i0 + 2) * NS + j] = s2;
    so[(i0 + 3) * NS + j] = s3;
}

// ---------------------------------------------------------------------------
extern "C" void kernel_launch(void* const* d_in, const int* in_sizes, int n_in,
                              void* d_out, int out_size, void* d_ws, size_t ws_size,
                              hipStream_t stream) {
    const float* x       = (const float*)d_in[0];
    const float* S0      = (const float*)d_in[1];
    const float* Wq      = (const float*)d_in[2];
    const float* Wk      = (const float*)d_in[3];
    const float* Wv      = (const float*)d_in[4];
    const float* Wa      = (const float*)d_in[5];
    const float* A_log   = (const float*)d_in[6];
    const float* dt_bias = (const float*)d_in[7];
    const float* Wout    = (const float*)d_in[8];

    float* out  = (float*)d_out;
    float* Sout = out + (size_t)T_LEN * BB * DIM;

    // --- workspace layout (~162 MB peak) ---
    char* w = (char*)d_ws;
    auto alloc = [&](size_t bytes) {
        char* p = w; w += (bytes + 255) & ~(size_t)255; return p;
    };
    unsigned short* xh  = (unsigned short*)alloc((size_t)MROWS * DIM * 2);  // 16.8 MB
    unsigned short* xl  = (unsigned short*)alloc((size_t)MROWS * DIM * 2);  // 16.8 MB
    unsigned short* Wbh = (unsigned short*)alloc((size_t)KD * DIM * 2);     // 3.67 MB (reused)
    unsigned short* Wbl = (unsigned short*)alloc((size_t)KD * DIM * 2);     // 3.67 MB (reused)
    float* kf           = (float*)alloc((size_t)MROWS * KD * 4);            // 58.7 MB
    float* vf           = (float*)alloc((size_t)MROWS * KD * 4);            // 58.7 MB
    unsigned short* Woh = (unsigned short*)alloc((size_t)DIM * KD * 2);     // 3.67 MB
    // Sq (fp16, 29.4 MB) aliases xh+xl (33.6 MB): x dead after last proj GEMM.
    unsigned short* Sq  = xh;

    // --- d_out head as scratch for q (fp16) + decay: dead before out GEMM ---
    unsigned short* qh  = (unsigned short*)d_out;                 // 29.36 MB
    float* decayb       = (float*)((char*)d_out + (size_t)MROWS * KD * 2); // 1.83 MB
    // (29.36 + 1.83 = 31.2 MB <= 33.55 MB out region; Sout at tail is disjoint)

    auto casts = [&](const float* src, unsigned short* hi, unsigned short* lo, size_t n) {
        int n8 = (int)(n / 8);
        cast_split_kernel<<<(n8 + 255) / 256, 256, 0, stream>>>(src, hi, lo, n8);
    };

    casts(x, xh, xl, (size_t)MROWS * DIM);

    // k projection -> fp32 [B][H][T][NS]
    casts(Wk, Wbh, Wbl, (size_t)KD * DIM);
    proj_gemm_kernel<<<dim3(14, 64), 256, 0, stream>>>(
        xh, xl, Wbh, Wbl, A_log, dt_bias, kf, nullptr, nullptr, 0);
    // v projection -> fp32 [B][H][T][NS]
    casts(Wv, Wbh, Wbl, (size_t)KD * DIM);
    proj_gemm_kernel<<<dim3(14, 64), 256, 0, stream>>>(
        xh, xl, Wbh, Wbl, A_log, dt_bias, vf, nullptr, nullptr, 0);
    // q projection -> fp16 [B][H][T][NS] (d_out scratch)
    casts(Wq, Wbh, Wbl, (size_t)KD * DIM);
    proj_gemm_kernel<<<dim3(14, 64), 256, 0, stream>>>(
        xh, xl, Wbh, Wbl, A_log, dt_bias, nullptr, qh, nullptr, 1);
    // decay -> fp32 [B][H][T] (d_out scratch)
    casts(Wa, Wbh, Wbl, (size_t)HH * DIM);
    proj_gemm_kernel<<<dim3(1, 64), 256, 0, stream>>>(
        xh, xl, Wbh, Wbl, A_log, dt_bias, nullptr, nullptr, decayb, 2);

    // Wout -> fp16
    {
        int n8 = (int)((size_t)DIM * KD / 8);
        cast_half_kernel<<<(n8 + 255) / 256, 256, 0, stream>>>(Wout, Woh, n8);
    }

    l2norm_f32_kernel<<<(MROWS * HH + 255) / 256, 256, 0, stream>>>(kf);
    l2norm_f16_kernel<<<(MROWS * HH + 255) / 256, 256, 0, stream>>>(qh);

    scan_kernel<<<BB * HH, 256, 0, stream>>>(kf, qh, vf, decayb, S0, Sq, Sout);

    out_gemm_kernel<<<dim3(8, 64), 256, 0, stream>>>(Sq, Woh, out);
}

// Round 7
// 889.854 us; speedup vs baseline: 2.7729x; 1.6028x over previous
//
#include <hip/hip_runtime.h>

// ---------------------------------------------------------------------------
// E89 ResidualStateCell.
// Precision architecture (recurrence-critical channels get ~fp32):
//   k, v, decay  -> split-bf16 (hi+lo) MFMA GEMM, fp32 storage   [feed S]
//   q, Sq, Wout  -> fp16 (read-out only, local error ~1e-4 rel)  [don't feed S]
//   scan         -> fp32 registers, v_exp/v_rcp tanh (~1ulp), DPP reductions
// Scan pipelining: operands staged chunk-wise (16 steps) into a 4-deep LDS
// ring via global_load_lds, 2 chunks ahead, counted vmcnt (never 0 in-loop)
// + raw s_barrier. This keeps in-flight data out of VGPRs so the compiler
// can't collapse the prefetch (round-6 lesson: VGPR=48 proved the 8-deep
// register pipeline was never allocated -> ~800 cy/step exposed latency).
// Layout: k,v,q transposed [B][H][T][NS], decay [B][H][T] (contiguous streams).
// Memory plan: ws ~162 MB; q fp16 + decay live in d_out head (dead before
// the final out-GEMM overwrites it; Sout tail disjoint).
// ---------------------------------------------------------------------------

typedef __attribute__((ext_vector_type(8))) __bf16 bf16x8;
typedef __attribute__((ext_vector_type(8))) _Float16 f16x8;
typedef __attribute__((ext_vector_type(4))) float f32x4;

#define T_LEN 2048
#define BB 4
#define HH 56
#define NS 32
#define DIM 1024
#define KD 1792            // H*NS
#define MROWS 8192         // T_LEN*BB
#define CH 16              // scan chunk (steps)
#define NCHUNK (T_LEN / CH)

#define VMCNT(N) asm volatile("s_waitcnt vmcnt(" #N ")" ::: "memory")

__device__ __forceinline__ float bf2f(unsigned short u) {
    return __uint_as_float(((unsigned int)u) << 16);
}
__device__ __forceinline__ unsigned short f2bf(float f) {
    unsigned int u = __float_as_uint(f);
    u += 0x7fffu + ((u >> 16) & 1u);          // round-to-nearest-even
    return (unsigned short)(u >> 16);
}
__device__ __forceinline__ unsigned short f2h(float f) {
    union { _Float16 h; unsigned short u; } cv;
    cv.h = (_Float16)f;                       // RNE
    return cv.u;
}
__device__ __forceinline__ float h2f(unsigned short u) {
    union { unsigned short u; _Float16 h; } cv;
    cv.u = u;
    return (float)cv.h;
}

// tanh via v_exp_f32 (2^x) directly: tanh(x) = 1 - 2/(1+2^(2*log2e*x))
__device__ __forceinline__ float tanh_fast(float x) {
    float e = __builtin_amdgcn_exp2f(x * 2.885390081777927f);
    float r = __builtin_amdgcn_rcpf(e + 1.0f);
    return fmaf(-2.0f, r, 1.0f);
}

// Sum across each aligned group of 8 lanes, pure-VALU DPP butterfly.
__device__ __forceinline__ float dpp_sum8(float x) {
    int t;
    t = __builtin_amdgcn_update_dpp(0, __float_as_int(x), 0xB1, 0xf, 0xf, true);
    x += __int_as_float(t);
    t = __builtin_amdgcn_update_dpp(0, __float_as_int(x), 0x4E, 0xf, 0xf, true);
    x += __int_as_float(t);
    t = __builtin_amdgcn_update_dpp(0, __float_as_int(x), 0x141, 0xf, 0xf, true);
    x += __int_as_float(t);
    return x;
}

__device__ __forceinline__ void gload_lds16(const void* g, void* l) {
    __builtin_amdgcn_global_load_lds(
        (const __attribute__((address_space(1))) unsigned int*)g,
        (__attribute__((address_space(3))) unsigned int*)l, 16, 0, 0);
}
__device__ __forceinline__ void gload_lds4(const void* g, void* l) {
    __builtin_amdgcn_global_load_lds(
        (const __attribute__((address_space(1))) unsigned int*)g,
        (__attribute__((address_space(3))) unsigned int*)l, 4, 0, 0);
}

// ---------------------------------------------------------------------------
// f32 -> (bf16 hi, bf16 lo) split cast, 8 elements / thread
// ---------------------------------------------------------------------------
__global__ void cast_split_kernel(const float* __restrict__ in,
                                  unsigned short* __restrict__ hi,
                                  unsigned short* __restrict__ lo, int n8) {
    int i = blockIdx.x * blockDim.x + threadIdx.x;
    if (i >= n8) return;
    const float4* p = (const float4*)in + (size_t)i * 2;
    float4 a = p[0], b = p[1];
    float xs[8] = {a.x, a.y, a.z, a.w, b.x, b.y, b.z, b.w};
    unsigned int ho[4], lv[4];
#pragma unroll
    for (int c = 0; c < 4; ++c) {
        unsigned short h0 = f2bf(xs[2 * c]);
        unsigned short h1 = f2bf(xs[2 * c + 1]);
        unsigned short l0 = f2bf(xs[2 * c] - bf2f(h0));
        unsigned short l1 = f2bf(xs[2 * c + 1] - bf2f(h1));
        ho[c] = (unsigned int)h0 | ((unsigned int)h1 << 16);
        lv[c] = (unsigned int)l0 | ((unsigned int)l1 << 16);
    }
    ((uint4*)hi)[i] = (uint4){ho[0], ho[1], ho[2], ho[3]};
    ((uint4*)lo)[i] = (uint4){lv[0], lv[1], lv[2], lv[3]};
}

// ---------------------------------------------------------------------------
// f32 -> fp16 cast, 8 elements / thread (for Wout)
// ---------------------------------------------------------------------------
__global__ void cast_half_kernel(const float* __restrict__ in,
                                 unsigned short* __restrict__ out, int n8) {
    int i = blockIdx.x * blockDim.x + threadIdx.x;
    if (i >= n8) return;
    const float4* p = (const float4*)in + (size_t)i * 2;
    float4 a = p[0], b = p[1];
    uint4 o;
    o.x = (unsigned int)f2h(a.x) | ((unsigned int)f2h(a.y) << 16);
    o.y = (unsigned int)f2h(a.z) | ((unsigned int)f2h(a.w) << 16);
    o.z = (unsigned int)f2h(b.x) | ((unsigned int)f2h(b.y) << 16);
    o.w = (unsigned int)f2h(b.z) | ((unsigned int)f2h(b.w) << 16);
    ((uint4*)out)[i] = o;
}

// ---------------------------------------------------------------------------
// Split MFMA GEMM core: Y[m,n] = sum_k A[m,k]*B[n,k], A=Ah+Al, B=Bh+Bl.
// 128x128 tile, BK=32, 256 threads = 4 waves (2x2), 16x16x32 bf16 MFMA x3.
// ---------------------------------------------------------------------------
__device__ __forceinline__ void gemm_split(
    const unsigned short* __restrict__ Ah, const unsigned short* __restrict__ Al,
    const unsigned short* __restrict__ Bh, const unsigned short* __restrict__ Bl,
    int m0, int n0, int K, int bmax,
    unsigned short* AsH, unsigned short* AsL,
    unsigned short* BsH, unsigned short* BsL,
    f32x4 (&acc)[4][4]) {
    const int tid  = threadIdx.x;
    const int lane = tid & 63;
    const int wave = tid >> 6;
    const int wm = wave >> 1, wn = wave & 1;
    const int lr = lane & 15, lkb = lane >> 4;

#pragma unroll
    for (int fr = 0; fr < 4; ++fr)
#pragma unroll
        for (int fc = 0; fc < 4; ++fc) acc[fr][fc] = (f32x4){0.f, 0.f, 0.f, 0.f};

    auto stage = [&](int kt) {
#pragma unroll
        for (int c = 0; c < 2; ++c) {
            int i = c * 256 + tid;
            int r = i >> 2, kk = (i & 3) << 3;
            size_t ao = (size_t)(m0 + r) * K + kt + kk;
            int br = n0 + r; if (br > bmax) br = bmax;
            size_t bo = (size_t)br * K + kt + kk;
            gload_lds16(Ah + ao, AsH + i * 8);
            gload_lds16(Al + ao, AsL + i * 8);
            gload_lds16(Bh + bo, BsH + i * 8);
            gload_lds16(Bl + bo, BsL + i * 8);
        }
    };

    stage(0);
    const int nk = K >> 5;
    for (int t = 0; t < nk; ++t) {
        __syncthreads();                       // drains vmcnt -> LDS tiles ready
        bf16x8 ah[4], al[4], bh[4], bl[4];
#pragma unroll
        for (int f = 0; f < 4; ++f) {
            int ai = (wm * 64 + f * 16 + lr) * 32 + lkb * 8;
            int bi = (wn * 64 + f * 16 + lr) * 32 + lkb * 8;
            ah[f] = *(const bf16x8*)(AsH + ai);
            al[f] = *(const bf16x8*)(AsL + ai);
            bh[f] = *(const bf16x8*)(BsH + bi);
            bl[f] = *(const bf16x8*)(BsL + bi);
        }
#pragma unroll
        for (int fr = 0; fr < 4; ++fr)
#pragma unroll
            for (int fc = 0; fc < 4; ++fc) {
                acc[fr][fc] = __builtin_amdgcn_mfma_f32_16x16x32_bf16(
                    ah[fr], bh[fc], acc[fr][fc], 0, 0, 0);
                acc[fr][fc] = __builtin_amdgcn_mfma_f32_16x16x32_bf16(
                    ah[fr], bl[fc], acc[fr][fc], 0, 0, 0);
                acc[fr][fc] = __builtin_amdgcn_mfma_f32_16x16x32_bf16(
                    al[fr], bh[fc], acc[fr][fc], 0, 0, 0);
            }
        __syncthreads();                       // all waves done reading LDS
        if (t + 1 < nk) stage((t + 1) << 5);
    }
}

// ---------------------------------------------------------------------------
// Projection GEMM over x (M=8192, K=1024).  Row m = t*BB + b.
// mode 0: silu -> fp32 dstF at [B][H][T][NS]     (k, v — recurrence-critical)
// mode 1: silu -> fp16 dstH at [B][H][T][NS]     (q — read-out only)
// mode 2: decay -> fp32 decayb at [B][H][T]      (n < 56)
// ---------------------------------------------------------------------------
__global__ __launch_bounds__(256) void proj_gemm_kernel(
    const unsigned short* __restrict__ xh, const unsigned short* __restrict__ xl,
    const unsigned short* __restrict__ Bh, const unsigned short* __restrict__ Bl,
    const float* __restrict__ A_log, const float* __restrict__ dt_bias,
    float* __restrict__ dstF, unsigned short* __restrict__ dstH,
    float* __restrict__ decayb, int mode) {
    __shared__ __align__(16) unsigned short AsH[128 * 32];
    __shared__ __align__(16) unsigned short AsL[128 * 32];
    __shared__ __align__(16) unsigned short BsH[128 * 32];
    __shared__ __align__(16) unsigned short BsL[128 * 32];

    int m0 = blockIdx.y * 128;
    int n0 = blockIdx.x * 128;
    int bmax = (mode == 2) ? (HH - 1) : (KD - 1);

    f32x4 acc[4][4];
    gemm_split(xh, xl, Bh, Bl, m0, n0, DIM, bmax, AsH, AsL, BsH, BsL, acc);

    const int lane = threadIdx.x & 63, wave = threadIdx.x >> 6;
    const int wm = wave >> 1, wn = wave & 1, lr = lane & 15, lkb = lane >> 4;

#pragma unroll
    for (int fr = 0; fr < 4; ++fr)
#pragma unroll
        for (int fc = 0; fc < 4; ++fc)
#pragma unroll
            for (int v = 0; v < 4; ++v) {
                int m = m0 + wm * 64 + fr * 16 + lkb * 4 + v;   // m = t*4 + b
                int n = n0 + wn * 64 + fc * 16 + lr;
                int t = m >> 2, b = m & 3;
                float y = acc[fr][fc][v];
                if (mode == 0) {
                    int h = n >> 5, i = n & 31;
                    float s = y / (1.f + __expf(-y));          // silu
                    dstF[(((size_t)(b * HH + h)) * T_LEN + t) * NS + i] = s;
                } else if (mode == 1) {
                    int h = n >> 5, i = n & 31;
                    float s = y / (1.f + __expf(-y));
                    dstH[(((size_t)(b * HH + h)) * T_LEN + t) * NS + i] = f2h(s);
                } else if (n < HH) {
                    float z = y + dt_bias[n];
                    float sp = (z > 20.f) ? z : log1pf(__expf(z));   // softplus
                    decayb[((size_t)(b * HH + n)) * T_LEN + t] =
                        __expf(-__expf(A_log[n]) * sp);
                }
            }
}

// ---------------------------------------------------------------------------
// Output GEMM (fp16): out = Sq @ Wout^T, f32 store.
// ---------------------------------------------------------------------------
__global__ __launch_bounds__(256) void out_gemm_kernel(
    const unsigned short* __restrict__ Sq, const unsigned short* __restrict__ Wo,
    float* __restrict__ out) {
    __shared__ __align__(16) unsigned short As[128 * 32];
    __shared__ __align__(16) unsigned short Bs[128 * 32];
    int m0 = blockIdx.y * 128, n0 = blockIdx.x * 128;

    const int tid  = threadIdx.x;
    const int lane = tid & 63;
    const int wave = tid >> 6;
    const int wm = wave >> 1, wn = wave & 1;
    const int lr = lane & 15, lkb = lane >> 4;

    f32x4 acc[4][4];
#pragma unroll
    for (int fr = 0; fr < 4; ++fr)
#pragma unroll
        for (int fc = 0; fc < 4; ++fc) acc[fr][fc] = (f32x4){0.f, 0.f, 0.f, 0.f};

    auto stage = [&](int kt) {
#pragma unroll
        for (int c = 0; c < 2; ++c) {
            int i = c * 256 + tid;
            int r = i >> 2, kk = (i & 3) << 3;
            gload_lds16(Sq + (size_t)(m0 + r) * KD + kt + kk, As + i * 8);
            gload_lds16(Wo + (size_t)(n0 + r) * KD + kt + kk, Bs + i * 8);
        }
    };

    stage(0);
    const int nk = KD >> 5;
    for (int t = 0; t < nk; ++t) {
        __syncthreads();
        f16x8 af[4], bf[4];
#pragma unroll
        for (int f = 0; f < 4; ++f) {
            af[f] = *(const f16x8*)(As + (wm * 64 + f * 16 + lr) * 32 + lkb * 8);
            bf[f] = *(const f16x8*)(Bs + (wn * 64 + f * 16 + lr) * 32 + lkb * 8);
        }
#pragma unroll
        for (int fr = 0; fr < 4; ++fr)
#pragma unroll
            for (int fc = 0; fc < 4; ++fc)
                acc[fr][fc] = __builtin_amdgcn_mfma_f32_16x16x32_f16(
                    af[fr], bf[fc], acc[fr][fc], 0, 0, 0);
        __syncthreads();
        if (t + 1 < nk) stage((t + 1) << 5);
    }

#pragma unroll
    for (int fr = 0; fr < 4; ++fr)
#pragma unroll
        for (int fc = 0; fc < 4; ++fc)
#pragma unroll
            for (int v = 0; v < 4; ++v) {
                int m = m0 + wm * 64 + fr * 16 + lkb * 4 + v;
                int n = n0 + wn * 64 + fc * 16 + lr;
                out[(size_t)m * DIM + n] = acc[fr][fc][v];
            }
}

// ---------------------------------------------------------------------------
// L2 normalization over NS=32 (transposed layout: rows contiguous).
// ---------------------------------------------------------------------------
__global__ void l2norm_f32_kernel(float* __restrict__ buf) {
    int g = blockIdx.x * blockDim.x + threadIdx.x;
    const int NG = MROWS * HH;
    if (g >= NG) return;
    float* p = buf + (size_t)g * NS;

    float4 u[8];
#pragma unroll
    for (int c = 0; c < 8; ++c) u[c] = ((const float4*)p)[c];
    float ss = 0.f;
#pragma unroll
    for (int c = 0; c < 8; ++c) {
        ss = fmaf(u[c].x, u[c].x, ss); ss = fmaf(u[c].y, u[c].y, ss);
        ss = fmaf(u[c].z, u[c].z, ss); ss = fmaf(u[c].w, u[c].w, ss);
    }
    float sc = 1.f / fmaxf(sqrtf(ss), 1e-12f);
#pragma unroll
    for (int c = 0; c < 8; ++c) {
        u[c].x *= sc; u[c].y *= sc; u[c].z *= sc; u[c].w *= sc;
        ((float4*)p)[c] = u[c];
    }
}

__global__ void l2norm_f16_kernel(unsigned short* __restrict__ buf) {
    int g = blockIdx.x * blockDim.x + threadIdx.x;
    const int NG = MROWS * HH;
    if (g >= NG) return;
    unsigned short* p = buf + (size_t)g * NS;

    uint4 u[4];
#pragma unroll
    for (int c = 0; c < 4; ++c) u[c] = ((const uint4*)p)[c];
    float ss = 0.f;
    auto acc2 = [&](unsigned int w) {
        float a = h2f((unsigned short)(w & 0xffff));
        float b = h2f((unsigned short)(w >> 16));
        ss = fmaf(a, a, ss); ss = fmaf(b, b, ss);
    };
#pragma unroll
    for (int c = 0; c < 4; ++c) { acc2(u[c].x); acc2(u[c].y); acc2(u[c].z); acc2(u[c].w); }
    float sc = 1.f / fmaxf(sqrtf(ss), 1e-12f);
    auto scl = [&](unsigned int w) -> unsigned int {
        unsigned int lo = f2h(h2f((unsigned short)(w & 0xffff)) * sc);
        unsigned int hi = f2h(h2f((unsigned short)(w >> 16)) * sc);
        return lo | (hi << 16);
    };
#pragma unroll
    for (int c = 0; c < 4; ++c) {
        u[c].x = scl(u[c].x); u[c].y = scl(u[c].y);
        u[c].z = scl(u[c].z); u[c].w = scl(u[c].w);
        ((uint4*)p)[c] = u[c];
    }
}

// ---------------------------------------------------------------------------
// Sequential scan with LDS-ring pipelining.
// Block bh: k/v/q at [bh][t][NS] (contiguous), decay at [bh][t].
// 4-deep chunk ring (CH=16 steps), staged 2 ahead via global_load_lds:
//   wave0: k (2x16B-instr = 2KB)   wave1: v (2KB)
//   wave2: q (1x16B-instr = 1KB)   wave3: d (1x4B-instr, 64B used)
// Counted vmcnt (Sq stores also count: 16/chunk) + raw s_barrier per chunk.
// ---------------------------------------------------------------------------
__global__ __launch_bounds__(256, 1) void scan_kernel(
    const float* __restrict__ kf, const unsigned short* __restrict__ qh,
    const float* __restrict__ vf, const float* __restrict__ decayb,
    const float* __restrict__ S0, unsigned short* __restrict__ Sq,
    float* __restrict__ Sout) {
    __shared__ __align__(16) float          kbuf[4][CH][NS];   // 8 KB
    __shared__ __align__(16) float          vbuf[4][CH][NS];   // 8 KB
    __shared__ __align__(16) unsigned short qbuf[4][CH][NS];   // 4 KB
    __shared__ __align__(16) float          dbuf[4][64];       // 1 KB (64B/chunk used)

    const int bh = blockIdx.x;                 // 0..223  (= b*HH + h)
    const int b = bh / HH, h = bh - b * HH;
    const int tid = threadIdx.x;
    const int lane = tid & 63, wave = tid >> 6;
    const int j = tid >> 3, sub = tid & 7, i0 = sub << 2;

    const float* Sp = S0 + (size_t)bh * NS * NS;
    float s0 = Sp[(i0 + 0) * NS + j];
    float s1 = Sp[(i0 + 1) * NS + j];
    float s2 = Sp[(i0 + 2) * NS + j];
    float s3 = Sp[(i0 + 3) * NS + j];

    const size_t base  = (size_t)bh * T_LEN * NS;
    const size_t dbase = (size_t)bh * T_LEN;
    const size_t cbcol = (size_t)h * NS;       // Sq column base

    // Stage chunk c into ring slot c&3 (wave-specialized).
    auto stage = [&](int c) {
        int s = c & 3;
        if (wave == 0) {
            const float* src = kf + base + (size_t)c * CH * NS;   // 512 f32
            gload_lds16(src + lane * 4,       &kbuf[s][0][0] + lane * 4);
            gload_lds16(src + 256 + lane * 4, &kbuf[s][8][0] + lane * 4);
        } else if (wave == 1) {
            const float* src = vf + base + (size_t)c * CH * NS;
            gload_lds16(src + lane * 4,       &vbuf[s][0][0] + lane * 4);
            gload_lds16(src + 256 + lane * 4, &vbuf[s][8][0] + lane * 4);
        } else if (wave == 2) {
            const unsigned short* src = qh + base + (size_t)c * CH * NS; // 512 u16
            gload_lds16(src + lane * 8, &qbuf[s][0][0] + lane * 8);
        } else {
            const float* src = decayb + dbase + (size_t)c * CH;   // 16 f32 used
            gload_lds4(src + lane, &dbuf[s][0] + lane);           // 48 tail lanes:
        }                                                          // harmless junk
    };

    stage(0);
    stage(1);
    VMCNT(0);
    __builtin_amdgcn_s_barrier();

    for (int c = 0; c < NCHUNK; ++c) {
        if (c + 2 < NCHUNK) stage(c + 2);
        // Counted wait: newest {stage(c+2): n_w} + {Sq stores of chunk c-1: 16}
        // may stay in flight; everything older (incl. chunk c's staging) drains.
        if (wave < 2) { VMCNT(18); } else { VMCNT(17); }
        __builtin_amdgcn_s_barrier();
        __builtin_amdgcn_sched_barrier(0);

        const int s = c & 3;
        // Hoist all LDS reads for this chunk into registers (static indices).
        float4 kr[CH]; uint2 qr[CH]; float vr[CH], dr[CH];
#pragma unroll
        for (int p = 0; p < CH; ++p) {
            kr[p] = *(const float4*)(&kbuf[s][p][i0]);
            qr[p] = *(const uint2*)(&qbuf[s][p][i0]);
            vr[p] = vbuf[s][p][j];
            dr[p] = dbuf[s][p];
        }
#pragma unroll
        for (int p = 0; p < CH; ++p) {
            const int t = c * CH + p;
            float k0 = kr[p].x, k1 = kr[p].y, k2 = kr[p].z, k3 = kr[p].w;
            float q0 = h2f((unsigned short)(qr[p].x & 0xffff));
            float q1 = h2f((unsigned short)(qr[p].x >> 16));
            float q2 = h2f((unsigned short)(qr[p].y & 0xffff));
            float q3 = h2f((unsigned short)(qr[p].y >> 16));
            float vj = vr[p];
            float d  = dr[p];

            // retrieved_j = sum_i S[i][j]*k_i  (tree partial + DPP 8-lane sum)
            float r = fmaf(k1, s1, k0 * s0) + fmaf(k3, s3, k2 * s2);
            r = dpp_sum8(r);
            float delta = vj - r;

            float a0 = fmaf(d, s0, k0 * delta);
            float a1 = fmaf(d, s1, k1 * delta);
            float a2 = fmaf(d, s2, k2 * delta);
            float a3 = fmaf(d, s3, k3 * delta);
            s0 += tanh_fast(a0); s1 += tanh_fast(a1);
            s2 += tanh_fast(a2); s3 += tanh_fast(a3);

            // Sq_j = sum_i S[i][j]*q_i
            float o = fmaf(q1, s1, q0 * s0) + fmaf(q3, s3, q2 * s2);
            o = dpp_sum8(o);
            if (sub == 0) {
                size_t ro = ((size_t)t * BB + b) * KD + cbcol;
                Sq[ro + j] = f2h(o);
            }
        }
    }

    float* so = Sout + (size_t)bh * NS * NS;
    so[(i0 + 0) * NS + j] = s0;
    so[(i0 + 1) * NS + j] = s1;
    so[(i0 + 2) * NS + j] = s2;
    so[(i0 + 3) * NS + j] = s3;
}

// ---------------------------------------------------------------------------
extern "C" void kernel_launch(void* const* d_in, const int* in_sizes, int n_in,
                              void* d_out, int out_size, void* d_ws, size_t ws_size,
                              hipStream_t stream) {
    const float* x       = (const float*)d_in[0];
    const float* S0      = (const float*)d_in[1];
    const float* Wq      = (const float*)d_in[2];
    const float* Wk      = (const float*)d_in[3];
    const float* Wv      = (const float*)d_in[4];
    const float* Wa      = (const float*)d_in[5];
    const float* A_log   = (const float*)d_in[6];
    const float* dt_bias = (const float*)d_in[7];
    const float* Wout    = (const float*)d_in[8];

    float* out  = (float*)d_out;
    float* Sout = out + (size_t)T_LEN * BB * DIM;

    // --- workspace layout (~162 MB peak) ---
    char* w = (char*)d_ws;
    auto alloc = [&](size_t bytes) {
        char* p = w; w += (bytes + 255) & ~(size_t)255; return p;
    };
    unsigned short* xh  = (unsigned short*)alloc((size_t)MROWS * DIM * 2);  // 16.8 MB
    unsigned short* xl  = (unsigned short*)alloc((size_t)MROWS * DIM * 2);  // 16.8 MB
    unsigned short* Wbh = (unsigned short*)alloc((size_t)KD * DIM * 2);     // 3.67 MB (reused)
    unsigned short* Wbl = (unsigned short*)alloc((size_t)KD * DIM * 2);     // 3.67 MB (reused)
    float* kf           = (float*)alloc((size_t)MROWS * KD * 4);            // 58.7 MB
    float* vf           = (float*)alloc((size_t)MROWS * KD * 4);            // 58.7 MB
    unsigned short* Woh = (unsigned short*)alloc((size_t)DIM * KD * 2);     // 3.67 MB
    // Sq (fp16, 29.4 MB) aliases xh+xl (33.6 MB): x dead after last proj GEMM.
    unsigned short* Sq  = xh;

    // --- d_out head as scratch for q (fp16) + decay: dead before out GEMM ---
    unsigned short* qh  = (unsigned short*)d_out;                 // 29.36 MB
    float* decayb       = (float*)((char*)d_out + (size_t)MROWS * KD * 2); // 1.83 MB
    // (29.36 + 1.83 = 31.2 MB <= 34.5 MB out region; Sout at tail is disjoint;
    //  scan's d-staging tail over-read of 188 B stays inside d_out.)

    auto casts = [&](const float* src, unsigned short* hi, unsigned short* lo, size_t n) {
        int n8 = (int)(n / 8);
        cast_split_kernel<<<(n8 + 255) / 256, 256, 0, stream>>>(src, hi, lo, n8);
    };

    casts(x, xh, xl, (size_t)MROWS * DIM);

    // k projection -> fp32 [B][H][T][NS]
    casts(Wk, Wbh, Wbl, (size_t)KD * DIM);
    proj_gemm_kernel<<<dim3(14, 64), 256, 0, stream>>>(
        xh, xl, Wbh, Wbl, A_log, dt_bias, kf, nullptr, nullptr, 0);
    // v projection -> fp32 [B][H][T][NS]
    casts(Wv, Wbh, Wbl, (size_t)KD * DIM);
    proj_gemm_kernel<<<dim3(14, 64), 256, 0, stream>>>(
        xh, xl, Wbh, Wbl, A_log, dt_bias, vf, nullptr, nullptr, 0);
    // q projection -> fp16 [B][H][T][NS] (d_out scratch)
    casts(Wq, Wbh, Wbl, (size_t)KD * DIM);
    proj_gemm_kernel<<<dim3(14, 64), 256, 0, stream>>>(
        xh, xl, Wbh, Wbl, A_log, dt_bias, nullptr, qh, nullptr, 1);
    // decay -> fp32 [B][H][T] (d_out scratch)
    casts(Wa, Wbh, Wbl, (size_t)HH * DIM);
    proj_gemm_kernel<<<dim3(1, 64), 256, 0, stream>>>(
        xh, xl, Wbh, Wbl, A_log, dt_bias, nullptr, nullptr, decayb, 2);

    // Wout -> fp16
    {
        int n8 = (int)((size_t)DIM * KD / 8);
        cast_half_kernel<<<(n8 + 255) / 256, 256, 0, stream>>>(Wout, Woh, n8);
    }

    l2norm_f32_kernel<<<(MROWS * HH + 255) / 256, 256, 0, stream>>>(kf);
    l2norm_f16_kernel<<<(MROWS * HH + 255) / 256, 256, 0, stream>>>(qh);

    scan_kernel<<<BB * HH, 256, 0, stream>>>(kf, qh, vf, decayb, S0, Sq, Sout);

    out_gemm_kernel<<<dim3(8, 64), 256, 0, stream>>>(Sq, Woh, out);
}

// Round 8
// 793.642 us; speedup vs baseline: 3.1090x; 1.1212x over previous
//
#include <hip/hip_runtime.h>

// ---------------------------------------------------------------------------
// E89 ResidualStateCell.
// Precision: k,v,decay (feed the recurrence) via split-bf16 (hi+lo) MFMA ->
// fp32; q,Sq,Wout (read-out only) via fp16 MFMA. Scan fp32 with fast tanh.
// Scan pipelining: 4-deep LDS chunk ring (global_load_lds, counted vmcnt)
// + explicit 4-step register double-buffer inside each chunk (R7 lesson:
// VGPR=76 proved the 16-step hoist was sunk; name the buffers, keep indices
// static, and the compiler keeps ds_reads ahead of the compute).
// Layout: k,v,q transposed [B][H][T][NS], decay [B][H][T].
// Memory: ws ~165 MB. q fp16 + decay live in d_out head (dead before the
// final out-GEMM overwrites it). x-fp16 aliases vf head; Sq aliases xh/xl.
// ---------------------------------------------------------------------------

typedef __attribute__((ext_vector_type(8))) __bf16 bf16x8;
typedef __attribute__((ext_vector_type(8))) _Float16 f16x8;
typedef __attribute__((ext_vector_type(4))) float f32x4;

#define T_LEN 2048
#define BB 4
#define HH 56
#define NS 32
#define DIM 1024
#define KD 1792            // H*NS
#define MROWS 8192         // T_LEN*BB
#define CH 16              // scan chunk (steps)
#define NCHUNK (T_LEN / CH)

#define VMCNT(N) asm volatile("s_waitcnt vmcnt(" #N ")" ::: "memory")

__device__ __forceinline__ float bf2f(unsigned short u) {
    return __uint_as_float(((unsigned int)u) << 16);
}
__device__ __forceinline__ unsigned short f2bf(float f) {
    unsigned int u = __float_as_uint(f);
    u += 0x7fffu + ((u >> 16) & 1u);          // round-to-nearest-even
    return (unsigned short)(u >> 16);
}
__device__ __forceinline__ unsigned short f2h(float f) {
    union { _Float16 h; unsigned short u; } cv;
    cv.h = (_Float16)f;                       // RNE
    return cv.u;
}
__device__ __forceinline__ float h2f(unsigned short u) {
    union { unsigned short u; _Float16 h; } cv;
    cv.u = u;
    return (float)cv.h;
}

// tanh via v_exp_f32 (2^x): tanh(x) = 1 - 2/(1+2^(2*log2e*x))
__device__ __forceinline__ float tanh_fast(float x) {
    float e = __builtin_amdgcn_exp2f(x * 2.885390081777927f);
    float r = __builtin_amdgcn_rcpf(e + 1.0f);
    return fmaf(-2.0f, r, 1.0f);
}

// Sum across each aligned group of 8 lanes, pure-VALU DPP butterfly.
__device__ __forceinline__ float dpp_sum8(float x) {
    int t;
    t = __builtin_amdgcn_update_dpp(0, __float_as_int(x), 0xB1, 0xf, 0xf, true);
    x += __int_as_float(t);
    t = __builtin_amdgcn_update_dpp(0, __float_as_int(x), 0x4E, 0xf, 0xf, true);
    x += __int_as_float(t);
    t = __builtin_amdgcn_update_dpp(0, __float_as_int(x), 0x141, 0xf, 0xf, true);
    x += __int_as_float(t);
    return x;
}

__device__ __forceinline__ void gload_lds16(const void* g, void* l) {
    __builtin_amdgcn_global_load_lds(
        (const __attribute__((address_space(1))) unsigned int*)g,
        (__attribute__((address_space(3))) unsigned int*)l, 16, 0, 0);
}
__device__ __forceinline__ void gload_lds4(const void* g, void* l) {
    __builtin_amdgcn_global_load_lds(
        (const __attribute__((address_space(1))) unsigned int*)g,
        (__attribute__((address_space(3))) unsigned int*)l, 4, 0, 0);
}

// ---------------------------------------------------------------------------
// f32 -> (bf16 hi, bf16 lo, fp16) triple cast for x, 8 elements / thread
// ---------------------------------------------------------------------------
__global__ void cast_split3_kernel(const float* __restrict__ in,
                                   unsigned short* __restrict__ hi,
                                   unsigned short* __restrict__ lo,
                                   unsigned short* __restrict__ h16, int n8) {
    int i = blockIdx.x * blockDim.x + threadIdx.x;
    if (i >= n8) return;
    const float4* p = (const float4*)in + (size_t)i * 2;
    float4 a = p[0], b = p[1];
    float xs[8] = {a.x, a.y, a.z, a.w, b.x, b.y, b.z, b.w};
    unsigned int ho[4], lv[4], hv[4];
#pragma unroll
    for (int c = 0; c < 4; ++c) {
        unsigned short h0 = f2bf(xs[2 * c]);
        unsigned short h1 = f2bf(xs[2 * c + 1]);
        unsigned short l0 = f2bf(xs[2 * c] - bf2f(h0));
        unsigned short l1 = f2bf(xs[2 * c + 1] - bf2f(h1));
        ho[c] = (unsigned int)h0 | ((unsigned int)h1 << 16);
        lv[c] = (unsigned int)l0 | ((unsigned int)l1 << 16);
        hv[c] = (unsigned int)f2h(xs[2 * c]) | ((unsigned int)f2h(xs[2 * c + 1]) << 16);
    }
    ((uint4*)hi)[i]  = (uint4){ho[0], ho[1], ho[2], ho[3]};
    ((uint4*)lo)[i]  = (uint4){lv[0], lv[1], lv[2], lv[3]};
    ((uint4*)h16)[i] = (uint4){hv[0], hv[1], hv[2], hv[3]};
}

// ---------------------------------------------------------------------------
// f32 -> (bf16 hi, bf16 lo) split cast, 8 elements / thread
// ---------------------------------------------------------------------------
__global__ void cast_split_kernel(const float* __restrict__ in,
                                  unsigned short* __restrict__ hi,
                                  unsigned short* __restrict__ lo, int n8) {
    int i = blockIdx.x * blockDim.x + threadIdx.x;
    if (i >= n8) return;
    const float4* p = (const float4*)in + (size_t)i * 2;
    float4 a = p[0], b = p[1];
    float xs[8] = {a.x, a.y, a.z, a.w, b.x, b.y, b.z, b.w};
    unsigned int ho[4], lv[4];
#pragma unroll
    for (int c = 0; c < 4; ++c) {
        unsigned short h0 = f2bf(xs[2 * c]);
        unsigned short h1 = f2bf(xs[2 * c + 1]);
        unsigned short l0 = f2bf(xs[2 * c] - bf2f(h0));
        unsigned short l1 = f2bf(xs[2 * c + 1] - bf2f(h1));
        ho[c] = (unsigned int)h0 | ((unsigned int)h1 << 16);
        lv[c] = (unsigned int)l0 | ((unsigned int)l1 << 16);
    }
    ((uint4*)hi)[i] = (uint4){ho[0], ho[1], ho[2], ho[3]};
    ((uint4*)lo)[i] = (uint4){lv[0], lv[1], lv[2], lv[3]};
}

// ---------------------------------------------------------------------------
// f32 -> fp16 cast, 8 elements / thread
// ---------------------------------------------------------------------------
__global__ void cast_half_kernel(const float* __restrict__ in,
                                 unsigned short* __restrict__ out, int n8) {
    int i = blockIdx.x * blockDim.x + threadIdx.x;
    if (i >= n8) return;
    const float4* p = (const float4*)in + (size_t)i * 2;
    float4 a = p[0], b = p[1];
    uint4 o;
    o.x = (unsigned int)f2h(a.x) | ((unsigned int)f2h(a.y) << 16);
    o.y = (unsigned int)f2h(a.z) | ((unsigned int)f2h(a.w) << 16);
    o.z = (unsigned int)f2h(b.x) | ((unsigned int)f2h(b.y) << 16);
    o.w = (unsigned int)f2h(b.z) | ((unsigned int)f2h(b.w) << 16);
    ((uint4*)out)[i] = o;
}

// ---------------------------------------------------------------------------
// Split MFMA GEMM core: Y[m,n] = sum_k A[m,k]*B[n,k], A=Ah+Al, B=Bh+Bl.
// 128x128 tile, BK=32, 256 threads = 4 waves (2x2), 16x16x32 bf16 MFMA x3.
// ---------------------------------------------------------------------------
__device__ __forceinline__ void gemm_split(
    const unsigned short* __restrict__ Ah, const unsigned short* __restrict__ Al,
    const unsigned short* __restrict__ Bh, const unsigned short* __restrict__ Bl,
    int m0, int n0, int K, int bmax,
    unsigned short* AsH, unsigned short* AsL,
    unsigned short* BsH, unsigned short* BsL,
    f32x4 (&acc)[4][4]) {
    const int tid  = threadIdx.x;
    const int lane = tid & 63;
    const int wave = tid >> 6;
    const int wm = wave >> 1, wn = wave & 1;
    const int lr = lane & 15, lkb = lane >> 4;

#pragma unroll
    for (int fr = 0; fr < 4; ++fr)
#pragma unroll
        for (int fc = 0; fc < 4; ++fc) acc[fr][fc] = (f32x4){0.f, 0.f, 0.f, 0.f};

    auto stage = [&](int kt) {
#pragma unroll
        for (int c = 0; c < 2; ++c) {
            int i = c * 256 + tid;
            int r = i >> 2, kk = (i & 3) << 3;
            size_t ao = (size_t)(m0 + r) * K + kt + kk;
            int br = n0 + r; if (br > bmax) br = bmax;
            size_t bo = (size_t)br * K + kt + kk;
            gload_lds16(Ah + ao, AsH + i * 8);
            gload_lds16(Al + ao, AsL + i * 8);
            gload_lds16(Bh + bo, BsH + i * 8);
            gload_lds16(Bl + bo, BsL + i * 8);
        }
    };

    stage(0);
    const int nk = K >> 5;
    for (int t = 0; t < nk; ++t) {
        __syncthreads();                       // drains vmcnt -> LDS tiles ready
        bf16x8 ah[4], al[4], bh[4], bl[4];
#pragma unroll
        for (int f = 0; f < 4; ++f) {
            int ai = (wm * 64 + f * 16 + lr) * 32 + lkb * 8;
            int bi = (wn * 64 + f * 16 + lr) * 32 + lkb * 8;
            ah[f] = *(const bf16x8*)(AsH + ai);
            al[f] = *(const bf16x8*)(AsL + ai);
            bh[f] = *(const bf16x8*)(BsH + bi);
            bl[f] = *(const bf16x8*)(BsL + bi);
        }
#pragma unroll
        for (int fr = 0; fr < 4; ++fr)
#pragma unroll
            for (int fc = 0; fc < 4; ++fc) {
                acc[fr][fc] = __builtin_amdgcn_mfma_f32_16x16x32_bf16(
                    ah[fr], bh[fc], acc[fr][fc], 0, 0, 0);
                acc[fr][fc] = __builtin_amdgcn_mfma_f32_16x16x32_bf16(
                    ah[fr], bl[fc], acc[fr][fc], 0, 0, 0);
                acc[fr][fc] = __builtin_amdgcn_mfma_f32_16x16x32_bf16(
                    al[fr], bh[fc], acc[fr][fc], 0, 0, 0);
            }
        __syncthreads();                       // all waves done reading LDS
        if (t + 1 < nk) stage((t + 1) << 5);
    }
}

// ---------------------------------------------------------------------------
// Split projection (k or v) + optional decay tile.  Row m = t*BB + b.
// Tiles 0..13: silu -> fp32 dstF at [B][H][T][NS].
// Tile 14 (k launch only, grid.x=15): decay -> fp32 decayb at [B][H][T].
// ---------------------------------------------------------------------------
__global__ __launch_bounds__(256) void proj_split_kernel(
    const unsigned short* __restrict__ xh, const unsigned short* __restrict__ xl,
    const unsigned short* __restrict__ Wh, const unsigned short* __restrict__ Wl,
    const unsigned short* __restrict__ Wah, const unsigned short* __restrict__ Wal,
    const float* __restrict__ A_log, const float* __restrict__ dt_bias,
    float* __restrict__ dstF, float* __restrict__ decayb) {
    __shared__ __align__(16) unsigned short AsH[128 * 32];
    __shared__ __align__(16) unsigned short AsL[128 * 32];
    __shared__ __align__(16) unsigned short BsH[128 * 32];
    __shared__ __align__(16) unsigned short BsL[128 * 32];

    const int tile = blockIdx.x;
    const bool isdecay = (tile == 14);
    int m0 = blockIdx.y * 128;
    int n0 = isdecay ? 0 : tile * 128;
    int bmax = isdecay ? (HH - 1) : (KD - 1);
    const unsigned short* Bh = isdecay ? Wah : Wh;
    const unsigned short* Bl = isdecay ? Wal : Wl;

    f32x4 acc[4][4];
    gemm_split(xh, xl, Bh, Bl, m0, n0, DIM, bmax, AsH, AsL, BsH, BsL, acc);

    const int lane = threadIdx.x & 63, wave = threadIdx.x >> 6;
    const int wm = wave >> 1, wn = wave & 1, lr = lane & 15, lkb = lane >> 4;

#pragma unroll
    for (int fr = 0; fr < 4; ++fr)
#pragma unroll
        for (int fc = 0; fc < 4; ++fc)
#pragma unroll
            for (int v = 0; v < 4; ++v) {
                int m = m0 + wm * 64 + fr * 16 + lkb * 4 + v;   // m = t*4 + b
                int n = n0 + wn * 64 + fc * 16 + lr;
                int t = m >> 2, b = m & 3;
                float y = acc[fr][fc][v];
                if (!isdecay) {
                    int h = n >> 5, i = n & 31;
                    float s = y / (1.f + __expf(-y));          // silu
                    dstF[(((size_t)(b * HH + h)) * T_LEN + t) * NS + i] = s;
                } else if (n < HH) {
                    float z = y + dt_bias[n];
                    float sp = (z > 20.f) ? z : log1pf(__expf(z));   // softplus
                    decayb[((size_t)(b * HH + n)) * T_LEN + t] =
                        __expf(-__expf(A_log[n]) * sp);
                }
            }
}

// ---------------------------------------------------------------------------
// q projection, single fp16 MFMA (q is read-out-only): q = silu(x @ Wq^T),
// fp16 store at [B][H][T][NS].
// ---------------------------------------------------------------------------
__global__ __launch_bounds__(256) void q_gemm_f16_kernel(
    const unsigned short* __restrict__ xf, const unsigned short* __restrict__ Wqf,
    unsigned short* __restrict__ dstH) {
    __shared__ __align__(16) unsigned short As[128 * 32];
    __shared__ __align__(16) unsigned short Bs[128 * 32];
    int m0 = blockIdx.y * 128, n0 = blockIdx.x * 128;

    const int tid  = threadIdx.x;
    const int lane = tid & 63;
    const int wave = tid >> 6;
    const int wm = wave >> 1, wn = wave & 1;
    const int lr = lane & 15, lkb = lane >> 4;

    f32x4 acc[4][4];
#pragma unroll
    for (int fr = 0; fr < 4; ++fr)
#pragma unroll
        for (int fc = 0; fc < 4; ++fc) acc[fr][fc] = (f32x4){0.f, 0.f, 0.f, 0.f};

    auto stage = [&](int kt) {
#pragma unroll
        for (int c = 0; c < 2; ++c) {
            int i = c * 256 + tid;
            int r = i >> 2, kk = (i & 3) << 3;
            gload_lds16(xf + (size_t)(m0 + r) * DIM + kt + kk, As + i * 8);
            gload_lds16(Wqf + (size_t)(n0 + r) * DIM + kt + kk, Bs + i * 8);
        }
    };

    stage(0);
    const int nk = DIM >> 5;
    for (int t = 0; t < nk; ++t) {
        __syncthreads();
        f16x8 af[4], bf[4];
#pragma unroll
        for (int f = 0; f < 4; ++f) {
            af[f] = *(const f16x8*)(As + (wm * 64 + f * 16 + lr) * 32 + lkb * 8);
            bf[f] = *(const f16x8*)(Bs + (wn * 64 + f * 16 + lr) * 32 + lkb * 8);
        }
#pragma unroll
        for (int fr = 0; fr < 4; ++fr)
#pragma unroll
            for (int fc = 0; fc < 4; ++fc)
                acc[fr][fc] = __builtin_amdgcn_mfma_f32_16x16x32_f16(
                    af[fr], bf[fc], acc[fr][fc], 0, 0, 0);
        __syncthreads();
        if (t + 1 < nk) stage((t + 1) << 5);
    }

#pragma unroll
    for (int fr = 0; fr < 4; ++fr)
#pragma unroll
        for (int fc = 0; fc < 4; ++fc)
#pragma unroll
            for (int v = 0; v < 4; ++v) {
                int m = m0 + wm * 64 + fr * 16 + lkb * 4 + v;
                int n = n0 + wn * 64 + fc * 16 + lr;
                int t = m >> 2, b = m & 3, h = n >> 5, i = n & 31;
                float y = acc[fr][fc][v];
                float s = y / (1.f + __expf(-y));
                dstH[(((size_t)(b * HH + h)) * T_LEN + t) * NS + i] = f2h(s);
            }
}

// ---------------------------------------------------------------------------
// Output GEMM (fp16): out = Sq @ Wout^T, f32 store.
// ---------------------------------------------------------------------------
__global__ __launch_bounds__(256) void out_gemm_kernel(
    const unsigned short* __restrict__ Sq, const unsigned short* __restrict__ Wo,
    float* __restrict__ out) {
    __shared__ __align__(16) unsigned short As[128 * 32];
    __shared__ __align__(16) unsigned short Bs[128 * 32];
    int m0 = blockIdx.y * 128, n0 = blockIdx.x * 128;

    const int tid  = threadIdx.x;
    const int lane = tid & 63;
    const int wave = tid >> 6;
    const int wm = wave >> 1, wn = wave & 1;
    const int lr = lane & 15, lkb = lane >> 4;

    f32x4 acc[4][4];
#pragma unroll
    for (int fr = 0; fr < 4; ++fr)
#pragma unroll
        for (int fc = 0; fc < 4; ++fc) acc[fr][fc] = (f32x4){0.f, 0.f, 0.f, 0.f};

    auto stage = [&](int kt) {
#pragma unroll
        for (int c = 0; c < 2; ++c) {
            int i = c * 256 + tid;
            int r = i >> 2, kk = (i & 3) << 3;
            gload_lds16(Sq + (size_t)(m0 + r) * KD + kt + kk, As + i * 8);
            gload_lds16(Wo + (size_t)(n0 + r) * KD + kt + kk, Bs + i * 8);
        }
    };

    stage(0);
    const int nk = KD >> 5;
    for (int t = 0; t < nk; ++t) {
        __syncthreads();
        f16x8 af[4], bf[4];
#pragma unroll
        for (int f = 0; f < 4; ++f) {
            af[f] = *(const f16x8*)(As + (wm * 64 + f * 16 + lr) * 32 + lkb * 8);
            bf[f] = *(const f16x8*)(Bs + (wn * 64 + f * 16 + lr) * 32 + lkb * 8);
        }
#pragma unroll
        for (int fr = 0; fr < 4; ++fr)
#pragma unroll
            for (int fc = 0; fc < 4; ++fc)
                acc[fr][fc] = __builtin_amdgcn_mfma_f32_16x16x32_f16(
                    af[fr], bf[fc], acc[fr][fc], 0, 0, 0);
        __syncthreads();
        if (t + 1 < nk) stage((t + 1) << 5);
    }

#pragma unroll
    for (int fr = 0; fr < 4; ++fr)
#pragma unroll
        for (int fc = 0; fc < 4; ++fc)
#pragma unroll
            for (int v = 0; v < 4; ++v) {
                int m = m0 + wm * 64 + fr * 16 + lkb * 4 + v;
                int n = n0 + wn * 64 + fc * 16 + lr;
                out[(size_t)m * DIM + n] = acc[fr][fc][v];
            }
}

// ---------------------------------------------------------------------------
// L2 normalization over NS=32: g < NG -> fp32 k row; else fp16 q row.
// ---------------------------------------------------------------------------
__global__ void l2norm_kernel(float* __restrict__ kf,
                              unsigned short* __restrict__ qh) {
    int g = blockIdx.x * blockDim.x + threadIdx.x;
    const int NG = MROWS * HH;
    if (g >= 2 * NG) return;
    if (g < NG) {
        float* p = kf + (size_t)g * NS;
        float4 u[8];
#pragma unroll
        for (int c = 0; c < 8; ++c) u[c] = ((const float4*)p)[c];
        float ss = 0.f;
#pragma unroll
        for (int c = 0; c < 8; ++c) {
            ss = fmaf(u[c].x, u[c].x, ss); ss = fmaf(u[c].y, u[c].y, ss);
            ss = fmaf(u[c].z, u[c].z, ss); ss = fmaf(u[c].w, u[c].w, ss);
        }
        float sc = 1.f / fmaxf(sqrtf(ss), 1e-12f);
#pragma unroll
        for (int c = 0; c < 8; ++c) {
            u[c].x *= sc; u[c].y *= sc; u[c].z *= sc; u[c].w *= sc;
            ((float4*)p)[c] = u[c];
        }
    } else {
        unsigned short* p = qh + (size_t)(g - NG) * NS;
        uint4 u[4];
#pragma unroll
        for (int c = 0; c < 4; ++c) u[c] = ((const uint4*)p)[c];
        float ss = 0.f;
        auto acc2 = [&](unsigned int w) {
            float a = h2f((unsigned short)(w & 0xffff));
            float b = h2f((unsigned short)(w >> 16));
            ss = fmaf(a, a, ss); ss = fmaf(b, b, ss);
        };
#pragma unroll
        for (int c = 0; c < 4; ++c) { acc2(u[c].x); acc2(u[c].y); acc2(u[c].z); acc2(u[c].w); }
        float sc = 1.f / fmaxf(sqrtf(ss), 1e-12f);
        auto scl = [&](unsigned int w) -> unsigned int {
            unsigned int lo = f2h(h2f((unsigned short)(w & 0xffff)) * sc);
            unsigned int hi = f2h(h2f((unsigned short)(w >> 16)) * sc);
            return lo | (hi << 16);
        };
#pragma unroll
        for (int c = 0; c < 4; ++c) {
            u[c].x = scl(u[c].x); u[c].y = scl(u[c].y);
            u[c].z = scl(u[c].z); u[c].w = scl(u[c].w);
            ((uint4*)p)[c] = u[c];
        }
    }
}

// ---------------------------------------------------------------------------
// Sequential scan with LDS-ring + in-chunk register double-buffer.
// Block bh: k/v/q at [bh][t][NS] (contiguous), decay at [bh][t].
// 4-deep chunk ring (CH=16), staged 2 ahead (wave-specialized global_load_lds,
// counted vmcnt). Inside each chunk: 4-step groups, load g+1 while computing g
// (named A/B register sets, all indices static).
// ---------------------------------------------------------------------------
__global__ __launch_bounds__(256, 1) void scan_kernel(
    const float* __restrict__ kf, const unsigned short* __restrict__ qh,
    const float* __restrict__ vf, const float* __restrict__ decayb,
    const float* __restrict__ S0, unsigned short* __restrict__ Sq,
    float* __restrict__ Sout) {
    __shared__ __align__(16) float          kbuf[4][CH][NS];   // 8 KB
    __shared__ __align__(16) float          vbuf[4][CH][NS];   // 8 KB
    __shared__ __align__(16) unsigned short qbuf[4][CH][NS];   // 4 KB
    __shared__ __align__(16) float          dbuf[4][64];       // 1 KB

    const int bh = blockIdx.x;                 // 0..223  (= b*HH + h)
    const int b = bh / HH, h = bh - b * HH;
    const int tid = threadIdx.x;
    const int lane = tid & 63, wave = tid >> 6;
    const int j = tid >> 3, sub = tid & 7, i0 = sub << 2;

    const float* Sp = S0 + (size_t)bh * NS * NS;
    float s0 = Sp[(i0 + 0) * NS + j];
    float s1 = Sp[(i0 + 1) * NS + j];
    float s2 = Sp[(i0 + 2) * NS + j];
    float s3 = Sp[(i0 + 3) * NS + j];

    const size_t base  = (size_t)bh * T_LEN * NS;
    const size_t dbase = (size_t)bh * T_LEN;
    const size_t cbcol = (size_t)h * NS;       // Sq column base

    auto stage = [&](int c) {
        int s = c & 3;
        if (wave == 0) {
            const float* src = kf + base + (size_t)c * CH * NS;
            gload_lds16(src + lane * 4,       &kbuf[s][0][0] + lane * 4);
            gload_lds16(src + 256 + lane * 4, &kbuf[s][8][0] + lane * 4);
        } else if (wave == 1) {
            const float* src = vf + base + (size_t)c * CH * NS;
            gload_lds16(src + lane * 4,       &vbuf[s][0][0] + lane * 4);
            gload_lds16(src + 256 + lane * 4, &vbuf[s][8][0] + lane * 4);
        } else if (wave == 2) {
            const unsigned short* src = qh + base + (size_t)c * CH * NS;
            gload_lds16(src + lane * 8, &qbuf[s][0][0] + lane * 8);
        } else {
            const float* src = decayb + dbase + (size_t)c * CH;
            gload_lds4(src + lane, &dbuf[s][0] + lane);   // tail lanes: junk, unused
        }
    };

    stage(0);
    stage(1);
    VMCNT(0);
    __builtin_amdgcn_s_barrier();

    for (int c = 0; c < NCHUNK; ++c) {
        if (c + 2 < NCHUNK) stage(c + 2);
        // Counted wait: newest {stage(c+2)} + {Sq stores of chunk c-1: 16}
        // may stay in flight; chunk c's staging (older) is drained.
        if (wave < 2) { VMCNT(18); } else { VMCNT(17); }
        __builtin_amdgcn_s_barrier();
        __builtin_amdgcn_sched_barrier(0);

        const int s = c & 3;
        float4 kA[4], kB[4]; uint2 qA[4], qB[4]; float vA[4], vB[4], dA[4], dB[4];

#define LDG(KK, QQ, VV, DD, g)                                          \
        {                                                               \
            _Pragma("unroll")                                           \
            for (int p = 0; p < 4; ++p) {                               \
                KK[p] = *(const float4*)(&kbuf[s][(g) * 4 + p][i0]);    \
                QQ[p] = *(const uint2*)(&qbuf[s][(g) * 4 + p][i0]);     \
                VV[p] = vbuf[s][(g) * 4 + p][j];                        \
                DD[p] = dbuf[s][(g) * 4 + p];                           \
            }                                                           \
        }

#define CMP(KK, QQ, VV, DD, g)                                          \
        {                                                               \
            _Pragma("unroll")                                           \
            for (int p = 0; p < 4; ++p) {                               \
                const int t = c * CH + (g) * 4 + p;                     \
                float k0 = KK[p].x, k1 = KK[p].y, k2 = KK[p].z, k3 = KK[p].w; \
                float q0 = h2f((unsigned short)(QQ[p].x & 0xffff));     \
                float q1 = h2f((unsigned short)(QQ[p].x >> 16));        \
                float q2 = h2f((unsigned short)(QQ[p].y & 0xffff));     \
                float q3 = h2f((unsigned short)(QQ[p].y >> 16));        \
                float vj = VV[p];                                       \
                float d  = DD[p];                                       \
                float r = fmaf(k1, s1, k0 * s0) + fmaf(k3, s3, k2 * s2);\
                r = dpp_sum8(r);                                        \
                float delta = vj - r;                                   \
                float a0 = fmaf(d, s0, k0 * delta);                     \
                float a1 = fmaf(d, s1, k1 * delta);                     \
                float a2 = fmaf(d, s2, k2 * delta);                     \
                float a3 = fmaf(d, s3, k3 * delta);                     \
                s0 += tanh_fast(a0); s1 += tanh_fast(a1);               \
                s2 += tanh_fast(a2); s3 += tanh_fast(a3);               \
                float o = fmaf(q1, s1, q0 * s0) + fmaf(q3, s3, q2 * s2);\
                o = dpp_sum8(o);                                        \
                if (sub == 0) {                                         \
                    size_t ro = ((size_t)t * BB + b) * KD + cbcol;      \
                    Sq[ro + j] = f2h(o);                                \
                }                                                       \
            }                                                           \
        }

        LDG(kA, qA, vA, dA, 0);
        LDG(kB, qB, vB, dB, 1);
        CMP(kA, qA, vA, dA, 0);
        LDG(kA, qA, vA, dA, 2);
        CMP(kB, qB, vB, dB, 1);
        LDG(kB, qB, vB, dB, 3);
        CMP(kA, qA, vA, dA, 2);
        CMP(kB, qB, vB, dB, 3);
#undef LDG
#undef CMP
    }

    float* so = Sout + (size_t)bh * NS * NS;
    so[(i0 + 0) * NS + j] = s0;
    so[(i0 + 1) * NS + j] = s1;
    so[(i0 + 2) * NS + j] = s2;
    so[(i0 + 3) * NS + j] = s3;
}

// ---------------------------------------------------------------------------
extern "C" void kernel_launch(void* const* d_in, const int* in_sizes, int n_in,
                              void* d_out, int out_size, void* d_ws, size_t ws_size,
                              hipStream_t stream) {
    const float* x       = (const float*)d_in[0];
    const float* S0      = (const float*)d_in[1];
    const float* Wq      = (const float*)d_in[2];
    const float* Wk      = (const float*)d_in[3];
    const float* Wv      = (const float*)d_in[4];
    const float* Wa      = (const float*)d_in[5];
    const float* A_log   = (const float*)d_in[6];
    const float* dt_bias = (const float*)d_in[7];
    const float* Wout    = (const float*)d_in[8];

    float* out  = (float*)d_out;
    float* Sout = out + (size_t)T_LEN * BB * DIM;

    // --- workspace layout (~165 MB peak) ---
    char* w = (char*)d_ws;
    auto alloc = [&](size_t bytes) {
        char* p = w; w += (bytes + 255) & ~(size_t)255; return p;
    };
    unsigned short* xh  = (unsigned short*)alloc((size_t)MROWS * DIM * 2);  // 16.8 MB
    unsigned short* xl  = (unsigned short*)alloc((size_t)MROWS * DIM * 2);  // 16.8 MB
    unsigned short* Wbh = (unsigned short*)alloc((size_t)KD * DIM * 2);     // 3.67 MB (reused)
    unsigned short* Wbl = (unsigned short*)alloc((size_t)KD * DIM * 2);     // 3.67 MB (reused)
    unsigned short* Wah = (unsigned short*)alloc((size_t)HH * DIM * 2);     // 0.11 MB
    unsigned short* Wal = (unsigned short*)alloc((size_t)HH * DIM * 2);     // 0.11 MB
    float* kf           = (float*)alloc((size_t)MROWS * KD * 4);            // 58.7 MB
    float* vf           = (float*)alloc((size_t)MROWS * KD * 4);            // 58.7 MB
    unsigned short* Woh = (unsigned short*)alloc((size_t)DIM * KD * 2);     // 3.67 MB
    // Aliases: Sq (fp16) over xh/xl (x dead after last proj GEMM);
    //          x-fp16 over vf head (dead once v-proj runs, after q-proj).
    unsigned short* Sq   = xh;
    unsigned short* xf16 = (unsigned short*)vf;

    // --- d_out head as scratch for q (fp16) + decay: dead before out GEMM ---
    unsigned short* qh  = (unsigned short*)d_out;                 // 29.36 MB
    float* decayb       = (float*)((char*)d_out + (size_t)MROWS * KD * 2); // 1.83 MB

    // 1) x -> bf16 hi/lo + fp16 (fp16 copy aliased in vf head)
    {
        int n8 = (int)((size_t)MROWS * DIM / 8);
        cast_split3_kernel<<<(n8 + 255) / 256, 256, 0, stream>>>(x, xh, xl, xf16, n8);
    }
    // 2) q projection (single fp16 MFMA): Wq fp16 staged in Wbh
    {
        int n8 = (int)((size_t)KD * DIM / 8);
        cast_half_kernel<<<(n8 + 255) / 256, 256, 0, stream>>>(Wq, Wbh, n8);
        q_gemm_f16_kernel<<<dim3(14, 64), 256, 0, stream>>>(xf16, Wbh, qh);
    }
    // 3) k projection + decay (tile 14), split-bf16
    {
        int n8 = (int)((size_t)KD * DIM / 8);
        cast_split_kernel<<<(n8 + 255) / 256, 256, 0, stream>>>(Wk, Wbh, Wbl, n8);
        int n8a = (int)((size_t)HH * DIM / 8);
        cast_split_kernel<<<(n8a + 255) / 256, 256, 0, stream>>>(Wa, Wah, Wal, n8a);
        proj_split_kernel<<<dim3(15, 64), 256, 0, stream>>>(
            xh, xl, Wbh, Wbl, Wah, Wal, A_log, dt_bias, kf, decayb);
    }
    // 4) v projection (overwrites xf16 alias -- xf16 dead after q-proj)
    {
        int n8 = (int)((size_t)KD * DIM / 8);
        cast_split_kernel<<<(n8 + 255) / 256, 256, 0, stream>>>(Wv, Wbh, Wbl, n8);
        proj_split_kernel<<<dim3(14, 64), 256, 0, stream>>>(
            xh, xl, Wbh, Wbl, Wah, Wal, A_log, dt_bias, vf, decayb);
    }
    // 5) Wout -> fp16
    {
        int n8 = (int)((size_t)DIM * KD / 8);
        cast_half_kernel<<<(n8 + 255) / 256, 256, 0, stream>>>(Wout, Woh, n8);
    }
    // 6) l2norm (k fp32 + q fp16, one launch)
    l2norm_kernel<<<(2 * MROWS * HH + 255) / 256, 256, 0, stream>>>(kf, qh);
    // 7) scan
    scan_kernel<<<BB * HH, 256, 0, stream>>>(kf, qh, vf, decayb, S0, Sq, Sout);
    // 8) output GEMM
    out_gemm_kernel<<<dim3(8, 64), 256, 0, stream>>>(Sq, Woh, out);
}